// Round 4
// baseline (532.466 us; speedup 1.0000x reference)
//
#include <hip/hip_runtime.h>
#include <hip/hip_bf16.h>
#include <math.h>

typedef __hip_bfloat16 bf16;

__device__ __forceinline__ float b2f(bf16 v) { return __bfloat162float(v); }
__device__ __forceinline__ bf16  f2b(float v) { return __float2bfloat16(v); }

template<int F32>
__device__ __forceinline__ float ldf(const void* p, int i) {
    return F32 ? ((const float*)p)[i] : b2f(((const bf16*)p)[i]);
}
// clamp that also scrubs NaN to a finite value (fmaxf/fminf pick the non-NaN operand)
__device__ __forceinline__ float sclamp(float v, float lim) {
    return fminf(fmaxf(v, -lim), lim);
}

#define NEG_SLOPE 0.2f
#define LN_EPS 1e-5f

// ---------------- runtime format detection ----------------
// flags[0]: edge_index physically int64 (odd int32 words all zero)
// flags[1]: float tensors physically fp32 (x viewed as uint16: even positions are
//           low-mantissa garbage for fp32, plausible bf16 exponents for bf16 data).
//           Output dtype is assumed to match (dataset converted wholesale or not at all).
__global__ void detect_kernel(const int* __restrict__ ei,
                              const unsigned short* __restrict__ xu,
                              int* __restrict__ flags) {
    if (blockIdx.x != 0 || threadIdx.x != 0) return;
    int hi = 0, nz = 0;
    for (int i = 0; i < 8; ++i) { hi |= ei[2 * i + 1]; nz |= ei[2 * i]; }
    flags[0] = (hi == 0 && nz != 0) ? 1 : 0;
    int pl = 0;
    for (int i = 0; i < 32; ++i) {
        unsigned e = (xu[2 * i] >> 7) & 0xFF;   // bf16: exponent field; fp32-low-half: mantissa noise
        if (e >= 100 && e <= 140) pl++;
    }
    flags[1] = (pl >= 24) ? 0 : 1;
}

__device__ __forceinline__ int ld_idx(const int* ei, long long pos, int is64, int N) {
    int v = is64 ? ei[2 * pos] : ei[pos];
    return min(max(v, 0), N - 1);
}

// ---------------- CSR build ----------------

__global__ void hist_kernel(const int* __restrict__ ei, int E, int N,
                            const int* __restrict__ flags, int* __restrict__ cnt) {
    int e = blockIdx.x * blockDim.x + threadIdx.x;
    if (e >= E) return;
    int is64 = flags[0];
    atomicAdd(&cnt[ld_idx(ei, (long long)E + e, is64, N)], 1);
}

__global__ void scan_kernel(const int* __restrict__ cnt, int* __restrict__ rowptr,
                            int* __restrict__ cursor, int N) {
    __shared__ int sums[1024];
    int tid = threadIdx.x;
    int per = (N + 1023) >> 10;
    int base = tid * per;
    int local = 0;
    for (int i = 0; i < per; ++i) {
        int idx = base + i;
        if (idx < N) local += cnt[idx];
    }
    sums[tid] = local;
    __syncthreads();
    for (int off = 1; off < 1024; off <<= 1) {
        int v = (tid >= off) ? sums[tid - off] : 0;
        __syncthreads();
        sums[tid] += v;
        __syncthreads();
    }
    int run = (tid == 0) ? 0 : sums[tid - 1];
    for (int i = 0; i < per; ++i) {
        int idx = base + i;
        if (idx < N) { rowptr[idx] = run; cursor[idx] = run; run += cnt[idx]; }
    }
    if (tid == 0) rowptr[N] = sums[1023];
}

template<int F32>
__global__ void scatter_kernel(const int* __restrict__ ei, const void* __restrict__ attr,
                               int E, int N, const int* __restrict__ flags,
                               int* __restrict__ cursor,
                               int* __restrict__ csr_src, bf16* __restrict__ csr_attr) {
    if (flags[1] != F32) return;
    int e = blockIdx.x * blockDim.x + threadIdx.x;
    if (e >= E) return;
    int is64 = flags[0];
    int d = ld_idx(ei, (long long)E + e, is64, N);
    int s = ld_idx(ei, (long long)e, is64, N);
    int pos = atomicAdd(&cursor[d], 1);
    csr_src[pos] = s;
    csr_attr[pos] = f2b(ldf<F32>(attr, e));
}

// ---------------- Layer-1 aggregation; node transforms computed on the fly ----------------
// One wave per node (grid-stride). Lane l: slots j0=l (heads 0/1), j1=l+64 (heads 2/3),
// channel c=l&31. x is only N*2 values (cache-resident); xl[s] recomputed per edge.

template<int F32>
__global__ __launch_bounds__(256) void agg1_kernel(
    const int* __restrict__ flags,
    const int* __restrict__ rowptr, const int* __restrict__ csr_src,
    const bf16* __restrict__ csr_attr, const void* __restrict__ x,
    const void* W1l, const void* b1l, const void* W1r, const void* b1r,
    const void* We1, const void* att1, const void* bias1, const void* g1, const void* beta1,
    bf16* __restrict__ hout, int N) {
    if (flags[1] != F32) return;
    int gwave  = (blockIdx.x * blockDim.x + threadIdx.x) >> 6;
    int nwaves = (gridDim.x * blockDim.x) >> 6;
    int lane = threadIdx.x & 63;
    int j0 = lane, j1 = lane + 64, c = lane & 31;

    float wla0 = ldf<F32>(W1l, j0), wlb0 = ldf<F32>(W1l, 128 + j0), bl0 = ldf<F32>(b1l, j0);
    float wla1 = ldf<F32>(W1l, j1), wlb1 = ldf<F32>(W1l, 128 + j1), bl1 = ldf<F32>(b1l, j1);
    float wra0 = ldf<F32>(W1r, j0), wrb0 = ldf<F32>(W1r, 128 + j0), br0 = ldf<F32>(b1r, j0);
    float wra1 = ldf<F32>(W1r, j1), wrb1 = ldf<F32>(W1r, 128 + j1), br1 = ldf<F32>(b1r, j1);
    float we0 = ldf<F32>(We1, j0), we1 = ldf<F32>(We1, j1);
    float at0 = ldf<F32>(att1, j0), at1 = ldf<F32>(att1, j1);
    float bia = ldf<F32>(bias1, c), gg = ldf<F32>(g1, c), bb = ldf<F32>(beta1, c);

    for (int n = gwave; n < N; n += nwaves) {
        int beg = rowptr[n], end = rowptr[n + 1];
        float xn0 = ldf<F32>(x, 2 * n), xn1 = ldf<F32>(x, 2 * n + 1);
        float xr0 = fmaf(xn1, wrb0, fmaf(xn0, wra0, br0));
        float xr1 = fmaf(xn1, wrb1, fmaf(xn0, wra1, br1));

        float M0 = -INFINITY, M1 = -INFINITY;
        float S0 = 0.f, S1 = 0.f, A0 = 0.f, A1 = 0.f;

        for (int k = beg; k < end; ++k) {
            int s = csr_src[k];                 // broadcast load (wave-uniform addr)
            float a = b2f(csr_attr[k]);
            float xs0 = ldf<F32>(x, 2 * s), xs1 = ldf<F32>(x, 2 * s + 1);
            float v0 = sclamp(fmaf(xs1, wlb0, fmaf(xs0, wla0, bl0)), 1e15f);
            float v1 = sclamp(fmaf(xs1, wlb1, fmaf(xs0, wla1, bl1)), 1e15f);
            float m0 = v0 + xr0 + a * we0; m0 = m0 > 0.f ? m0 : NEG_SLOPE * m0;
            float m1 = v1 + xr1 + a * we1; m1 = m1 > 0.f ? m1 : NEG_SLOPE * m1;
            float p0 = sclamp(m0 * at0, 1e18f), p1 = sclamp(m1 * at1, 1e18f);
            #pragma unroll
            for (int off = 1; off < 32; off <<= 1) {   // per-head sum (stays in 32-lane half)
                p0 += __shfl_xor(p0, off, 64);
                p1 += __shfl_xor(p1, off, 64);
            }
            p0 = sclamp(p0, 1e30f); p1 = sclamp(p1, 1e30f);
            float nM0 = fmaxf(M0, p0);
            float sc0 = __expf(M0 - nM0);
            float e0  = __expf(p0 - nM0);
            S0 = S0 * sc0 + e0;  A0 = A0 * sc0 + e0 * v0;  M0 = nM0;
            float nM1 = fmaxf(M1, p1);
            float sc1 = __expf(M1 - nM1);
            float e1  = __expf(p1 - nM1);
            S1 = S1 * sc1 + e1;  A1 = A1 * sc1 + e1 * v1;  M1 = nM1;
        }

        float v0 = A0 / (S0 + 1e-16f);
        float v1 = A1 / (S1 + 1e-16f);
        float t = v0 + v1;
        t += __shfl_xor(t, 32, 64);          // all 4 heads for channel c
        float val = sclamp(t * 0.25f + bia, 1e15f);

        float mu = val;
        #pragma unroll
        for (int off = 1; off < 32; off <<= 1) mu += __shfl_xor(mu, off, 64);
        mu *= (1.f / 32.f);
        float d = val - mu;
        float var = d * d;
        #pragma unroll
        for (int off = 1; off < 32; off <<= 1) var += __shfl_xor(var, off, 64);
        var *= (1.f / 32.f);
        float y = d * rsqrtf(var + LN_EPS) * gg + bb;
        float h = y > 0.f ? y : expm1f(y);   // ELU
        if (lane < 32) hout[n * 32 + lane] = f2b(h);
    }
}

// ---------------- Layer-2 node transform, IN-PLACE over hbuf ----------------
// Thread n reads its 32 bf16 h-values (64 B) into registers, then overwrites the
// same 64 B with h2l[0..15] | h2r[0..15] (bf16). Per-thread exclusive region.

template<int F32>
__global__ __launch_bounds__(256) void node2_kernel(
    const int* __restrict__ flags, bf16* __restrict__ hbuf,
    const void* W2l, const void* b2l, const void* W2r, const void* b2r, int N) {
    if (flags[1] != F32) return;
    __shared__ float wl[32 * 16], wr[32 * 16], bl[16], br[16];
    int tid = threadIdx.x;
    for (int i = tid; i < 512; i += 256) { wl[i] = ldf<F32>(W2l, i); wr[i] = ldf<F32>(W2r, i); }
    if (tid < 16) { bl[tid] = ldf<F32>(b2l, tid); br[tid] = ldf<F32>(b2r, tid); }
    __syncthreads();
    int n = blockIdx.x * blockDim.x + tid;
    if (n >= N) return;
    float hv[32];
    #pragma unroll
    for (int cidx = 0; cidx < 32; ++cidx) hv[cidx] = b2f(hbuf[n * 32 + cidx]);
    float accl[16], accr[16];
    #pragma unroll
    for (int o = 0; o < 16; ++o) { accl[o] = bl[o]; accr[o] = br[o]; }
    #pragma unroll
    for (int cidx = 0; cidx < 32; ++cidx) {
        #pragma unroll
        for (int o = 0; o < 16; ++o) {
            accl[o] = fmaf(hv[cidx], wl[cidx * 16 + o], accl[o]);
            accr[o] = fmaf(hv[cidx], wr[cidx * 16 + o], accr[o]);
        }
    }
    #pragma unroll
    for (int o = 0; o < 16; ++o) {
        hbuf[n * 32 + o]      = f2b(accl[o]);   // h2l
        hbuf[n * 32 + 16 + o] = f2b(accr[o]);   // h2r
    }
}

// ---------------- Layer-2 aggregation: one wave per node, 4 sub-groups of 16 lanes ----
// Output dtype follows flags[1]: fp32 dataset -> fp32 out, bf16 dataset -> bf16 out.

template<int F32>
__global__ __launch_bounds__(256) void agg2_kernel(
    const int* __restrict__ flags,
    const int* __restrict__ rowptr, const int* __restrict__ csr_src,
    const bf16* __restrict__ csr_attr, const bf16* __restrict__ h2,
    const void* We2, const void* att2, const void* bias2, const void* g2, const void* beta2,
    void* __restrict__ out, int N) {
    if (flags[1] != F32) return;
    int gwave  = (blockIdx.x * blockDim.x + threadIdx.x) >> 6;
    int nwaves = (gridDim.x * blockDim.x) >> 6;
    int lane = threadIdx.x & 63;
    int g = lane >> 4;      // sub-group: one edge per round
    int t = lane & 15;      // channel

    float we = ldf<F32>(We2, t);
    float at = ldf<F32>(att2, t);
    float bia = ldf<F32>(bias2, t), gg = ldf<F32>(g2, t), bb = ldf<F32>(beta2, t);

    for (int n = gwave; n < N; n += nwaves) {
        int beg = rowptr[n], end = rowptr[n + 1];
        float xr = b2f(h2[n * 32 + 16 + t]);   // h2r

        float M = -INFINITY, S = 0.f, A = 0.f;
        for (int k = beg + g; k < end; k += 4) {
            int s = csr_src[k];
            float a = b2f(csr_attr[k]);
            float v = b2f(h2[s * 32 + t]);     // h2l
            float m = v + xr + a * we; m = m > 0.f ? m : NEG_SLOPE * m;
            float p = sclamp(m * at, 1e18f);
            #pragma unroll
            for (int off = 1; off < 16; off <<= 1) p += __shfl_xor(p, off, 64);
            p = sclamp(p, 1e30f);
            float nM = fmaxf(M, p);
            float sc = __expf(M - nM);
            float e  = __expf(p - nM);
            S = S * sc + e;
            A = A * sc + e * v;
            M = nM;
        }
        // merge the 4 sub-groups (softmax-merge); empty groups contribute exp(-inf)=0
        float Mg = M;
        Mg = fmaxf(Mg, __shfl_xor(Mg, 16, 64));
        Mg = fmaxf(Mg, __shfl_xor(Mg, 32, 64));
        if (Mg == -INFINITY) Mg = 0.f;
        float f = __expf(M - Mg);
        float Sg = S * f;
        Sg += __shfl_xor(Sg, 16, 64);
        Sg += __shfl_xor(Sg, 32, 64);
        float Ag = A * f;
        Ag += __shfl_xor(Ag, 16, 64);
        Ag += __shfl_xor(Ag, 32, 64);

        float val = sclamp(Ag / (Sg + 1e-16f) + bia, 1e15f);

        float mu = val;
        #pragma unroll
        for (int off = 1; off < 16; off <<= 1) mu += __shfl_xor(mu, off, 64);
        mu *= (1.f / 16.f);
        float d = val - mu;
        float var = d * d;
        #pragma unroll
        for (int off = 1; off < 16; off <<= 1) var += __shfl_xor(var, off, 64);
        var *= (1.f / 16.f);
        float y = d * rsqrtf(var + LN_EPS) * gg + bb;
        if (lane < 16) {
            if (F32) ((float*)out)[n * 16 + t] = y;
            else     ((bf16*)out)[n * 16 + t] = f2b(y);
        }
    }
}

// ---------------- host ----------------

static inline size_t align256(size_t x) { return (x + 255) & ~size_t(255); }

extern "C" void kernel_launch(void* const* d_in, const int* in_sizes, int n_in,
                              void* d_out, int out_size, void* d_ws, size_t ws_size,
                              hipStream_t stream) {
    const void* x     = d_in[0];
    const int*  ei    = (const int*)d_in[1];
    const void* eattr = d_in[2];
    const void* W1l   = d_in[3];
    const void* b1l   = d_in[4];
    const void* W1r   = d_in[5];
    const void* b1r   = d_in[6];
    const void* We1   = d_in[7];
    const void* att1  = d_in[8];
    const void* bias1 = d_in[9];
    const void* g1    = d_in[10];
    const void* beta1 = d_in[11];
    const void* W2l   = d_in[12];
    const void* b2l   = d_in[13];
    const void* W2r   = d_in[14];
    const void* b2r   = d_in[15];
    const void* We2   = d_in[16];
    const void* att2  = d_in[17];
    const void* bias2 = d_in[18];
    const void* g2    = d_in[19];
    const void* beta2 = d_in[20];

    const int N = in_sizes[0] / 2;   // x is (N,2)
    const int E = in_sizes[2];       // edge_attr is (E,1)

    // workspace layout (~9.8 MB at N=50000, E=1e6)
    char* ws = (char*)d_ws;
    size_t off = 0;
    int* flags     = (int*)(ws + off); off += align256(sizeof(int) * 2);
    int* cnt       = (int*)(ws + off); off += align256(sizeof(int) * (size_t)N);
    int* rowptr    = (int*)(ws + off); off += align256(sizeof(int) * (size_t)(N + 1));
    int* cursor    = (int*)(ws + off); off += align256(sizeof(int) * (size_t)N);
    int* csr_src   = (int*)(ws + off); off += align256(sizeof(int) * (size_t)E);
    bf16* csr_attr = (bf16*)(ws + off); off += align256(sizeof(bf16) * (size_t)E);
    bf16* hbuf     = (bf16*)(ws + off); off += align256(sizeof(bf16) * (size_t)N * 32);

    hipMemsetAsync(cnt, 0, sizeof(int) * (size_t)N, stream);
    detect_kernel<<<1, 64, 0, stream>>>(ei, (const unsigned short*)x, flags);

    int eb = (E + 255) / 256;
    hist_kernel<<<eb, 256, 0, stream>>>(ei, E, N, flags, cnt);
    scan_kernel<<<1, 1024, 0, stream>>>(cnt, rowptr, cursor, N);
    scatter_kernel<0><<<eb, 256, 0, stream>>>(ei, eattr, E, N, flags, cursor, csr_src, csr_attr);
    scatter_kernel<1><<<eb, 256, 0, stream>>>(ei, eattr, E, N, flags, cursor, csr_src, csr_attr);

    agg1_kernel<0><<<2048, 256, 0, stream>>>(flags, rowptr, csr_src, csr_attr, x,
                                             W1l, b1l, W1r, b1r, We1, att1, bias1, g1, beta1,
                                             hbuf, N);
    agg1_kernel<1><<<2048, 256, 0, stream>>>(flags, rowptr, csr_src, csr_attr, x,
                                             W1l, b1l, W1r, b1r, We1, att1, bias1, g1, beta1,
                                             hbuf, N);

    node2_kernel<0><<<(N + 255) / 256, 256, 0, stream>>>(flags, hbuf, W2l, b2l, W2r, b2r, N);
    node2_kernel<1><<<(N + 255) / 256, 256, 0, stream>>>(flags, hbuf, W2l, b2l, W2r, b2r, N);

    agg2_kernel<0><<<2048, 256, 0, stream>>>(flags, rowptr, csr_src, csr_attr, hbuf,
                                             We2, att2, bias2, g2, beta2, d_out, N);
    agg2_kernel<1><<<2048, 256, 0, stream>>>(flags, rowptr, csr_src, csr_attr, hbuf,
                                             We2, att2, bias2, g2, beta2, d_out, N);
}

// Round 5
// 451.898 us; speedup vs baseline: 1.1783x; 1.1783x over previous
//
#include <hip/hip_runtime.h>
#include <hip/hip_bf16.h>
#include <math.h>

typedef __hip_bfloat16 bf16;

__device__ __forceinline__ float b2f(bf16 v) { return __bfloat162float(v); }
__device__ __forceinline__ bf16  f2b(float v) { return __float2bfloat16(v); }

template<int F32>
__device__ __forceinline__ float ldf(const void* p, int i) {
    return F32 ? ((const float*)p)[i] : b2f(((const bf16*)p)[i]);
}
// clamp that also scrubs NaN (fmaxf/fminf pick the non-NaN operand)
__device__ __forceinline__ float sclamp(float v, float lim) {
    return fminf(fmaxf(v, -lim), lim);
}
// sum over the 16-lane group (lanes with same lane>>4)
__device__ __forceinline__ float red16(float v) {
    v += __shfl_xor(v, 1);
    v += __shfl_xor(v, 2);
    v += __shfl_xor(v, 4);
    v += __shfl_xor(v, 8);
    return v;
}

#define NEG_SLOPE 0.2f
#define LN_EPS 1e-5f

// ---------------- runtime format detection ----------------
// flags[0]: edge_index physically int64; flags[1]: float tensors physically fp32
__global__ void detect_kernel(const int* __restrict__ ei,
                              const unsigned short* __restrict__ xu,
                              int* __restrict__ flags) {
    if (blockIdx.x != 0 || threadIdx.x != 0) return;
    int hi = 0, nz = 0;
    for (int i = 0; i < 8; ++i) { hi |= ei[2 * i + 1]; nz |= ei[2 * i]; }
    flags[0] = (hi == 0 && nz != 0) ? 1 : 0;
    int pl = 0;
    for (int i = 0; i < 32; ++i) {
        unsigned e = (xu[2 * i] >> 7) & 0xFF;
        if (e >= 100 && e <= 140) pl++;
    }
    flags[1] = (pl >= 24) ? 0 : 1;
}

__device__ __forceinline__ int ld_idx(const int* ei, long long pos, int is64, int N) {
    int v = is64 ? ei[2 * pos] : ei[pos];
    return min(max(v, 0), N - 1);
}

// ---------------- CSR build ----------------

__global__ void hist_kernel(const int* __restrict__ ei, int E, int N,
                            const int* __restrict__ flags, int* __restrict__ cnt) {
    int e = blockIdx.x * blockDim.x + threadIdx.x;
    if (e >= E) return;
    int is64 = flags[0];
    atomicAdd(&cnt[ld_idx(ei, (long long)E + e, is64, N)], 1);
}

// converts cnt (counts) into cursor (start offsets) in place; writes rowptr
__global__ void scan_kernel(int* __restrict__ cnt, int* __restrict__ rowptr, int N) {
    __shared__ int sums[1024];
    int tid = threadIdx.x;
    int per = (N + 1023) >> 10;
    int base = tid * per;
    int local = 0;
    for (int i = 0; i < per; ++i) {
        int idx = base + i;
        if (idx < N) local += cnt[idx];
    }
    sums[tid] = local;
    __syncthreads();
    for (int off = 1; off < 1024; off <<= 1) {
        int v = (tid >= off) ? sums[tid - off] : 0;
        __syncthreads();
        sums[tid] += v;
        __syncthreads();
    }
    int run = (tid == 0) ? 0 : sums[tid - 1];
    for (int i = 0; i < per; ++i) {
        int idx = base + i;
        if (idx < N) { int c = cnt[idx]; rowptr[idx] = run; cnt[idx] = run; run += c; }
    }
    if (tid == 0) rowptr[N] = sums[1023];
}

template<int F32>
__device__ void scatter_body(const int* __restrict__ ei, const void* __restrict__ attr,
                             int E, int N, int is64, int* __restrict__ cursor,
                             int* __restrict__ csr_src, bf16* __restrict__ csr_attr) {
    int e = blockIdx.x * blockDim.x + threadIdx.x;
    if (e >= E) return;
    int d = ld_idx(ei, (long long)E + e, is64, N);
    int s = ld_idx(ei, (long long)e, is64, N);
    int pos = atomicAdd(&cursor[d], 1);
    csr_src[pos] = s;
    csr_attr[pos] = f2b(ldf<F32>(attr, e));
}

__global__ void scatter_kernel(const int* __restrict__ ei, const void* __restrict__ attr,
                               int E, int N, const int* __restrict__ flags,
                               int* __restrict__ cursor,
                               int* __restrict__ csr_src, bf16* __restrict__ csr_attr) {
    if (flags[1]) scatter_body<1>(ei, attr, E, N, flags[0], cursor, csr_src, csr_attr);
    else          scatter_body<0>(ei, attr, E, N, flags[0], cursor, csr_src, csr_attr);
}

// ---------------- Layer-1 aggregation ----------------
// Head-major: lane = h*16+q, h=lane>>4, q=lane&15. Lane handles channels
// ja=h*32+q, jb=ja+16. att.LeakyReLU(z) = 0.6 att.z (collapses to 3 FMA via
// precomputed per-head dots) + 0.4 att.|z| (per-channel). Value path is affine
// in (xs0,xs1,1): accumulate only S, Sum e*xs0, Sum e*xs1 per head.

template<int F32>
__device__ void agg1_body(
    const int* __restrict__ rowptr, const int* __restrict__ csr_src,
    const bf16* __restrict__ csr_attr, const void* __restrict__ x,
    const void* W1l, const void* b1l, const void* W1r, const void* b1r,
    const void* We1, const void* att1, const void* bias1, const void* g1v, const void* beta1,
    bf16* __restrict__ hout, int N) {
    int w0 = __builtin_amdgcn_readfirstlane((blockIdx.x * blockDim.x + threadIdx.x) >> 6);
    int NW = (gridDim.x * blockDim.x) >> 6;
    int lane = threadIdx.x & 63;
    int h = lane >> 4, q = lane & 15;
    int ja = h * 32 + q, jb = ja + 16;

    float wlaA = ldf<F32>(W1l, ja),      wlaB = ldf<F32>(W1l, jb);
    float wlbA = ldf<F32>(W1l, 128 + ja), wlbB = ldf<F32>(W1l, 128 + jb);
    float wraA = ldf<F32>(W1r, ja),      wraB = ldf<F32>(W1r, jb);
    float wrbA = ldf<F32>(W1r, 128 + ja), wrbB = ldf<F32>(W1r, 128 + jb);
    float blA = ldf<F32>(b1l, ja), blB = ldf<F32>(b1l, jb);
    float brA = ldf<F32>(b1r, ja), brB = ldf<F32>(b1r, jb);
    float weA = ldf<F32>(We1, ja), weB = ldf<F32>(We1, jb);
    float atA = ldf<F32>(att1, ja), atB = ldf<F32>(att1, jb);
    float aa4A = 0.4f * atA, aa4B = 0.4f * atB;
    float blbrA = blA + brA, blbrB = blB + brB;
    float P0 = 0.6f * red16(atA * wlaA + atB * wlaB);
    float P1 = 0.6f * red16(atA * wlbA + atB * wlbB);
    float Pw = 0.6f * red16(atA * weA + atB * weB);
    float Q0 = 0.6f * red16(atA * wraA + atB * wraB);
    float Q1 = 0.6f * red16(atA * wrbA + atB * wrbB);
    float Qc = 0.6f * red16(atA * blbrA + atB * blbrB);
    float biasA = ldf<F32>(bias1, q), biasB = ldf<F32>(bias1, q + 16);
    float gA = ldf<F32>(g1v, q), gB = ldf<F32>(g1v, q + 16);
    float beA = ldf<F32>(beta1, q), beB = ldf<F32>(beta1, q + 16);

    for (int n = w0; n < N; n += NW) {
        int beg = rowptr[n], end = rowptr[n + 1];
        float xd0 = ldf<F32>(x, 2 * n), xd1 = ldf<F32>(x, 2 * n + 1);
        float cA = fmaf(xd0, wraA, fmaf(xd1, wrbA, blbrA));
        float cB = fmaf(xd0, wraB, fmaf(xd1, wrbB, blbrB));
        float Kn = fmaf(xd0, Q0, fmaf(xd1, Q1, Qc));
        float S = 0.f, Sx0 = 0.f, Sx1 = 0.f;

        #pragma unroll 2
        for (int k = beg; k < end; ++k) {
            int s = csr_src[k];                 // scalar load (k wave-uniform)
            float a = b2f(csr_attr[k]);         // broadcast load
            float xs0 = ldf<F32>(x, 2 * s), xs1 = ldf<F32>(x, 2 * s + 1);
            float zA = fmaf(xs0, wlaA, fmaf(xs1, wlbA, fmaf(a, weA, cA)));
            float zB = fmaf(xs0, wlaB, fmaf(xs1, wlbB, fmaf(a, weB, cB)));
            float pabs = fmaf(fabsf(zA), aa4A, fabsf(zB) * aa4B);
            pabs = red16(pabs);                 // per-head sum over 32 channels
            float p = fmaf(xs0, P0, fmaf(xs1, P1, fmaf(a, Pw, Kn))) + pabs;
            p = sclamp(p, 60.f);
            float e = __expf(p);                // no max-subtraction: |logit|<=60
            S += e;
            Sx0 = fmaf(e, xs0, Sx0);
            Sx1 = fmaf(e, xs1, Sx1);
        }
        float inv = 1.0f / (S + 1e-16f);
        float R = S * inv, U0 = Sx0 * inv, U1 = Sx1 * inv;   // R=sum(alpha): 0 for isolated nodes
        float outA = fmaf(U0, wlaA, fmaf(U1, wlbA, R * blA));
        float outB = fmaf(U0, wlaB, fmaf(U1, wlbB, R * blB));
        // head mean: lanes {q, q+16, q+32, q+48} hold the 4 heads of channel q
        outA += __shfl_xor(outA, 16); outA += __shfl_xor(outA, 32);
        outB += __shfl_xor(outB, 16); outB += __shfl_xor(outB, 32);
        float valA = fmaf(0.25f, outA, biasA);
        float valB = fmaf(0.25f, outB, biasB);
        // LayerNorm over 32 channels (each group holds all 32 across its 16 lanes x 2 slots)
        float mu = red16(valA + valB) * (1.f / 32.f);
        float dA = valA - mu, dB = valB - mu;
        float var = red16(dA * dA + dB * dB) * (1.f / 32.f);
        float rs = rsqrtf(var + LN_EPS);
        float yA = fmaf(dA * rs, gA, beA);
        float yB = fmaf(dB * rs, gB, beB);
        float hA = yA > 0.f ? yA : expm1f(yA);   // ELU
        float hB = yB > 0.f ? yB : expm1f(yB);
        if (lane < 16) {
            hout[n * 32 + q]      = f2b(hA);
            hout[n * 32 + 16 + q] = f2b(hB);
        }
    }
}

__global__ __launch_bounds__(256) void agg1_kernel(
    const int* __restrict__ flags,
    const int* __restrict__ rowptr, const int* __restrict__ csr_src,
    const bf16* __restrict__ csr_attr, const void* __restrict__ x,
    const void* W1l, const void* b1l, const void* W1r, const void* b1r,
    const void* We1, const void* att1, const void* bias1, const void* g1v, const void* beta1,
    bf16* __restrict__ hout, int N) {
    if (flags[1]) agg1_body<1>(rowptr, csr_src, csr_attr, x, W1l, b1l, W1r, b1r,
                               We1, att1, bias1, g1v, beta1, hout, N);
    else          agg1_body<0>(rowptr, csr_src, csr_attr, x, W1l, b1l, W1r, b1r,
                               We1, att1, bias1, g1v, beta1, hout, N);
}

// ---------------- Layer-2 node transform, in-place over hbuf ----------------

template<int F32>
__device__ void node2_body(bf16* __restrict__ hbuf, float* wl, float* wr,
                           const void* W2l, const void* b2l, const void* W2r, const void* b2r,
                           int N) {
    __shared__ float bl[16], br[16];
    int tid = threadIdx.x;
    for (int i = tid; i < 512; i += 256) { wl[i] = ldf<F32>(W2l, i); wr[i] = ldf<F32>(W2r, i); }
    if (tid < 16) { bl[tid] = ldf<F32>(b2l, tid); br[tid] = ldf<F32>(b2r, tid); }
    __syncthreads();
    int n = blockIdx.x * blockDim.x + tid;
    if (n >= N) return;
    float hv[32];
    #pragma unroll
    for (int c = 0; c < 32; ++c) hv[c] = b2f(hbuf[n * 32 + c]);
    float accl[16], accr[16];
    #pragma unroll
    for (int o = 0; o < 16; ++o) { accl[o] = bl[o]; accr[o] = br[o]; }
    #pragma unroll
    for (int c = 0; c < 32; ++c) {
        #pragma unroll
        for (int o = 0; o < 16; ++o) {
            accl[o] = fmaf(hv[c], wl[c * 16 + o], accl[o]);
            accr[o] = fmaf(hv[c], wr[c * 16 + o], accr[o]);
        }
    }
    #pragma unroll
    for (int o = 0; o < 16; ++o) {
        hbuf[n * 32 + o]      = f2b(accl[o]);   // h2l
        hbuf[n * 32 + 16 + o] = f2b(accr[o]);   // h2r
    }
}

__global__ __launch_bounds__(256) void node2_kernel(
    const int* __restrict__ flags, bf16* __restrict__ hbuf,
    const void* W2l, const void* b2l, const void* W2r, const void* b2r, int N) {
    __shared__ float wl[512], wr[512];
    if (flags[1]) node2_body<1>(hbuf, wl, wr, W2l, b2l, W2r, b2r, N);
    else          node2_body<0>(hbuf, wl, wr, W2l, b2l, W2r, b2r, N);
}

// ---------------- Layer-2 aggregation: 4 sub-groups of 16 lanes ----------------

template<int F32>
__device__ void agg2_body(
    const int* __restrict__ rowptr, const int* __restrict__ csr_src,
    const bf16* __restrict__ csr_attr, const bf16* __restrict__ h2,
    const void* We2, const void* att2, const void* bias2, const void* g2v, const void* beta2,
    void* __restrict__ out, int N) {
    int w0 = __builtin_amdgcn_readfirstlane((blockIdx.x * blockDim.x + threadIdx.x) >> 6);
    int NW = (gridDim.x * blockDim.x) >> 6;
    int lane = threadIdx.x & 63;
    int g = lane >> 4, t = lane & 15;

    float we = ldf<F32>(We2, t), at = ldf<F32>(att2, t);
    float bia = ldf<F32>(bias2, t), gg = ldf<F32>(g2v, t), bb = ldf<F32>(beta2, t);

    for (int n = w0; n < N; n += NW) {
        int beg = rowptr[n], end = rowptr[n + 1];
        float xr = b2f(h2[n * 32 + 16 + t]);   // h2r

        float S = 0.f, A = 0.f;
        for (int k = beg + g; k < end; k += 4) {
            int s = csr_src[k];
            float a = b2f(csr_attr[k]);
            float v = b2f(h2[s * 32 + t]);     // h2l
            float m = fmaf(a, we, v + xr);
            m = fmaxf(m, NEG_SLOPE * m);       // LeakyReLU
            float p = red16(m * at);
            p = sclamp(p, 60.f);
            float e = __expf(p);
            S += e;
            A = fmaf(e, v, A);
        }
        // merge the 4 sub-groups (plain sums: no max-shift needed)
        S += __shfl_xor(S, 16); S += __shfl_xor(S, 32);
        A += __shfl_xor(A, 16); A += __shfl_xor(A, 32);
        float val = A / (S + 1e-16f) + bia;    // empty node -> 0 + bias

        float mu = red16(val) * (1.f / 16.f);
        float d = val - mu;
        float var = red16(d * d) * (1.f / 16.f);
        float y = fmaf(d * rsqrtf(var + LN_EPS), gg, bb);
        if (lane < 16) {
            if (F32) ((float*)out)[n * 16 + t] = y;
            else     ((bf16*)out)[n * 16 + t] = f2b(y);
        }
    }
}

__global__ __launch_bounds__(256) void agg2_kernel(
    const int* __restrict__ flags,
    const int* __restrict__ rowptr, const int* __restrict__ csr_src,
    const bf16* __restrict__ csr_attr, const bf16* __restrict__ h2,
    const void* We2, const void* att2, const void* bias2, const void* g2v, const void* beta2,
    void* __restrict__ out, int N) {
    if (flags[1]) agg2_body<1>(rowptr, csr_src, csr_attr, h2, We2, att2, bias2, g2v, beta2, out, N);
    else          agg2_body<0>(rowptr, csr_src, csr_attr, h2, We2, att2, bias2, g2v, beta2, out, N);
}

// ---------------- host ----------------

static inline size_t align256(size_t x) { return (x + 255) & ~size_t(255); }

extern "C" void kernel_launch(void* const* d_in, const int* in_sizes, int n_in,
                              void* d_out, int out_size, void* d_ws, size_t ws_size,
                              hipStream_t stream) {
    const void* x     = d_in[0];
    const int*  ei    = (const int*)d_in[1];
    const void* eattr = d_in[2];
    const void* W1l   = d_in[3];
    const void* b1l   = d_in[4];
    const void* W1r   = d_in[5];
    const void* b1r   = d_in[6];
    const void* We1   = d_in[7];
    const void* att1  = d_in[8];
    const void* bias1 = d_in[9];
    const void* g1    = d_in[10];
    const void* beta1 = d_in[11];
    const void* W2l   = d_in[12];
    const void* b2l   = d_in[13];
    const void* W2r   = d_in[14];
    const void* b2r   = d_in[15];
    const void* We2   = d_in[16];
    const void* att2  = d_in[17];
    const void* bias2 = d_in[18];
    const void* g2    = d_in[19];
    const void* beta2 = d_in[20];

    const int N = in_sizes[0] / 2;   // x is (N,2)
    const int E = in_sizes[2];       // edge_attr is (E,1)

    // workspace (~9.7 MB at N=50000, E=1e6 — same footprint as the passing r4 layout)
    char* ws = (char*)d_ws;
    size_t off = 0;
    int* flags     = (int*)(ws + off); off += align256(sizeof(int) * 2);
    int* cnt       = (int*)(ws + off); off += align256(sizeof(int) * (size_t)N);      // doubles as cursor
    int* rowptr    = (int*)(ws + off); off += align256(sizeof(int) * (size_t)(N + 1));
    int* csr_src   = (int*)(ws + off); off += align256(sizeof(int) * (size_t)E);
    bf16* csr_attr = (bf16*)(ws + off); off += align256(sizeof(bf16) * (size_t)E);
    bf16* hbuf     = (bf16*)(ws + off); off += align256(sizeof(bf16) * (size_t)N * 32);

    hipMemsetAsync(cnt, 0, sizeof(int) * (size_t)N, stream);
    detect_kernel<<<1, 64, 0, stream>>>(ei, (const unsigned short*)x, flags);

    int eb = (E + 255) / 256;
    hist_kernel<<<eb, 256, 0, stream>>>(ei, E, N, flags, cnt);
    scan_kernel<<<1, 1024, 0, stream>>>(cnt, rowptr, N);
    scatter_kernel<<<eb, 256, 0, stream>>>(ei, eattr, E, N, flags, cnt, csr_src, csr_attr);

    agg1_kernel<<<2048, 256, 0, stream>>>(flags, rowptr, csr_src, csr_attr, x,
                                          W1l, b1l, W1r, b1r, We1, att1, bias1, g1, beta1,
                                          hbuf, N);

    node2_kernel<<<(N + 255) / 256, 256, 0, stream>>>(flags, hbuf, W2l, b2l, W2r, b2r, N);

    agg2_kernel<<<2048, 256, 0, stream>>>(flags, rowptr, csr_src, csr_attr, hbuf,
                                          We2, att2, bias2, g2, beta2, d_out, N);
}

// Round 6
// 338.180 us; speedup vs baseline: 1.5745x; 1.3363x over previous
//
#include <hip/hip_runtime.h>
#include <hip/hip_bf16.h>
#include <math.h>

typedef __hip_bfloat16 bf16;

__device__ __forceinline__ float b2f(bf16 v) { return __bfloat162float(v); }
__device__ __forceinline__ bf16  f2b(float v) { return __float2bfloat16(v); }

template<int F32>
__device__ __forceinline__ float ldf(const void* p, int i) {
    return F32 ? ((const float*)p)[i] : b2f(((const bf16*)p)[i]);
}
// clamp that also scrubs NaN (fmaxf/fminf pick the non-NaN operand)
__device__ __forceinline__ float sclamp(float v, float lim) {
    return fminf(fmaxf(v, -lim), lim);
}
// sum over the 16-lane group (lanes with same lane>>4)
__device__ __forceinline__ float red16(float v) {
    v += __shfl_xor(v, 1);
    v += __shfl_xor(v, 2);
    v += __shfl_xor(v, 4);
    v += __shfl_xor(v, 8);
    return v;
}

#define NEG_SLOPE 0.2f
#define LN_EPS 1e-5f
#define SCAN_TILE 1024   // elements per scan block (256 thr x 4)

// ---------------- runtime format detection ----------------
// flags[0]: edge_index physically int64; flags[1]: float tensors physically fp32
__global__ void detect_kernel(const int* __restrict__ ei,
                              const unsigned short* __restrict__ xu,
                              int* __restrict__ flags) {
    if (blockIdx.x != 0 || threadIdx.x != 0) return;
    int hi = 0, nz = 0;
    for (int i = 0; i < 8; ++i) { hi |= ei[2 * i + 1]; nz |= ei[2 * i]; }
    flags[0] = (hi == 0 && nz != 0) ? 1 : 0;
    int pl = 0;
    for (int i = 0; i < 32; ++i) {
        unsigned e = (xu[2 * i] >> 7) & 0xFF;
        if (e >= 100 && e <= 140) pl++;
    }
    flags[1] = (pl >= 24) ? 0 : 1;
}

__device__ __forceinline__ int ld_idx(const int* ei, long long pos, int is64, int N) {
    int v = is64 ? ei[2 * pos] : ei[pos];
    return min(max(v, 0), N - 1);
}

// ---------------- CSR build ----------------

__global__ void hist_kernel(const int* __restrict__ ei, int E, int N,
                            const int* __restrict__ flags, int* __restrict__ cnt) {
    int e = blockIdx.x * blockDim.x + threadIdx.x;
    if (e >= E) return;
    int is64 = flags[0];
    atomicAdd(&cnt[ld_idx(ei, (long long)E + e, is64, N)], 1);
}

// ---- 3-phase multi-block exclusive scan of cnt -> rowptr + cursor(in place) ----

__global__ __launch_bounds__(256) void scan_partial(const int* __restrict__ cnt,
                                                    int* __restrict__ bsum, int N) {
    __shared__ int wsum[4];
    int b = blockIdx.x, tid = threadIdx.x;
    int base = b * SCAN_TILE + tid * 4;
    int4 v = make_int4(0, 0, 0, 0);
    if (base + 3 < N) v = *(const int4*)(cnt + base);
    else {
        if (base + 0 < N) v.x = cnt[base + 0];
        if (base + 1 < N) v.y = cnt[base + 1];
        if (base + 2 < N) v.z = cnt[base + 2];
    }
    int s = v.x + v.y + v.z + v.w;
    #pragma unroll
    for (int off = 1; off < 64; off <<= 1) s += __shfl_xor(s, off);
    if ((tid & 63) == 0) wsum[tid >> 6] = s;
    __syncthreads();
    if (tid == 0) bsum[b] = wsum[0] + wsum[1] + wsum[2] + wsum[3];
}

// single small block: exclusive-scan bsum[0..B) in place; rowptr[N] = total
__global__ void scan_bsum(int* __restrict__ bsum, int B, int* __restrict__ rowptr, int N) {
    __shared__ int sums[1024];
    int tid = threadIdx.x;
    sums[tid] = (tid < B) ? bsum[tid] : 0;
    __syncthreads();
    for (int off = 1; off < 1024; off <<= 1) {
        int v = (tid >= off) ? sums[tid - off] : 0;
        __syncthreads();
        sums[tid] += v;
        __syncthreads();
    }
    if (tid < B) bsum[tid] = (tid == 0) ? 0 : sums[tid - 1];
    if (tid == 0) rowptr[N] = sums[1023];
}

__global__ __launch_bounds__(256) void scan_final(int* __restrict__ cnt, int* __restrict__ rowptr,
                                                  const int* __restrict__ bsum, int N) {
    __shared__ int tsum[256];
    int b = blockIdx.x, tid = threadIdx.x;
    int base = b * SCAN_TILE + tid * 4;
    int4 v = make_int4(0, 0, 0, 0);
    if (base + 3 < N) v = *(const int4*)(cnt + base);
    else {
        if (base + 0 < N) v.x = cnt[base + 0];
        if (base + 1 < N) v.y = cnt[base + 1];
        if (base + 2 < N) v.z = cnt[base + 2];
    }
    tsum[tid] = v.x + v.y + v.z + v.w;
    __syncthreads();
    for (int off = 1; off < 256; off <<= 1) {
        int t = (tid >= off) ? tsum[tid - off] : 0;
        __syncthreads();
        tsum[tid] += t;
        __syncthreads();
    }
    int o0 = bsum[b] + ((tid == 0) ? 0 : tsum[tid - 1]);
    int o1 = o0 + v.x, o2 = o1 + v.y, o3 = o2 + v.z;
    if (base + 3 < N) {
        int4 o = make_int4(o0, o1, o2, o3);
        *(int4*)(rowptr + base) = o;
        *(int4*)(cnt + base) = o;          // cursor
    } else {
        if (base + 0 < N) { rowptr[base + 0] = o0; cnt[base + 0] = o0; }
        if (base + 1 < N) { rowptr[base + 1] = o1; cnt[base + 1] = o1; }
        if (base + 2 < N) { rowptr[base + 2] = o2; cnt[base + 2] = o2; }
    }
}

template<int F32>
__device__ void scatter_body(const int* __restrict__ ei, const void* __restrict__ attr,
                             int E, int N, int is64, int* __restrict__ cursor,
                             int* __restrict__ csr_src, bf16* __restrict__ csr_attr) {
    int e = blockIdx.x * blockDim.x + threadIdx.x;
    if (e >= E) return;
    int d = ld_idx(ei, (long long)E + e, is64, N);
    int s = ld_idx(ei, (long long)e, is64, N);
    int pos = atomicAdd(&cursor[d], 1);
    csr_src[pos] = s;
    csr_attr[pos] = f2b(ldf<F32>(attr, e));
}

__global__ void scatter_kernel(const int* __restrict__ ei, const void* __restrict__ attr,
                               int E, int N, const int* __restrict__ flags,
                               int* __restrict__ cursor,
                               int* __restrict__ csr_src, bf16* __restrict__ csr_attr) {
    if (flags[1]) scatter_body<1>(ei, attr, E, N, flags[0], cursor, csr_src, csr_attr);
    else          scatter_body<0>(ei, attr, E, N, flags[0], cursor, csr_src, csr_attr);
}

// ---------------- Layer-1 aggregation ----------------
// Head-major: lane = h*16+q. att.LeakyReLU(z) = 0.6 att.z (3 FMA via per-head dots)
// + 0.4 att.|z| (per-channel). Value path affine in (xs0,xs1,1): accumulate only
// S, Sum e*xs0, Sum e*xs1 per head.

template<int F32>
__device__ void agg1_body(
    const int* __restrict__ rowptr, const int* __restrict__ csr_src,
    const bf16* __restrict__ csr_attr, const void* __restrict__ x,
    const void* W1l, const void* b1l, const void* W1r, const void* b1r,
    const void* We1, const void* att1, const void* bias1, const void* g1v, const void* beta1,
    bf16* __restrict__ hout, int N) {
    int w0 = __builtin_amdgcn_readfirstlane((blockIdx.x * blockDim.x + threadIdx.x) >> 6);
    int NW = (gridDim.x * blockDim.x) >> 6;
    int lane = threadIdx.x & 63;
    int h = lane >> 4, q = lane & 15;
    int ja = h * 32 + q, jb = ja + 16;

    float wlaA = ldf<F32>(W1l, ja),      wlaB = ldf<F32>(W1l, jb);
    float wlbA = ldf<F32>(W1l, 128 + ja), wlbB = ldf<F32>(W1l, 128 + jb);
    float wraA = ldf<F32>(W1r, ja),      wraB = ldf<F32>(W1r, jb);
    float wrbA = ldf<F32>(W1r, 128 + ja), wrbB = ldf<F32>(W1r, 128 + jb);
    float blA = ldf<F32>(b1l, ja), blB = ldf<F32>(b1l, jb);
    float brA = ldf<F32>(b1r, ja), brB = ldf<F32>(b1r, jb);
    float weA = ldf<F32>(We1, ja), weB = ldf<F32>(We1, jb);
    float atA = ldf<F32>(att1, ja), atB = ldf<F32>(att1, jb);
    float aa4A = 0.4f * atA, aa4B = 0.4f * atB;
    float blbrA = blA + brA, blbrB = blB + brB;
    float P0 = 0.6f * red16(atA * wlaA + atB * wlaB);
    float P1 = 0.6f * red16(atA * wlbA + atB * wlbB);
    float Pw = 0.6f * red16(atA * weA + atB * weB);
    float Q0 = 0.6f * red16(atA * wraA + atB * wraB);
    float Q1 = 0.6f * red16(atA * wrbA + atB * wrbB);
    float Qc = 0.6f * red16(atA * blbrA + atB * blbrB);
    float biasA = ldf<F32>(bias1, q), biasB = ldf<F32>(bias1, q + 16);
    float gA = ldf<F32>(g1v, q), gB = ldf<F32>(g1v, q + 16);
    float beA = ldf<F32>(beta1, q), beB = ldf<F32>(beta1, q + 16);

    for (int n = w0; n < N; n += NW) {
        int beg = rowptr[n], end = rowptr[n + 1];
        float xd0 = ldf<F32>(x, 2 * n), xd1 = ldf<F32>(x, 2 * n + 1);
        float cA = fmaf(xd0, wraA, fmaf(xd1, wrbA, blbrA));
        float cB = fmaf(xd0, wraB, fmaf(xd1, wrbB, blbrB));
        float Kn = fmaf(xd0, Q0, fmaf(xd1, Q1, Qc));
        float S = 0.f, Sx0 = 0.f, Sx1 = 0.f;

        #pragma unroll 2
        for (int k = beg; k < end; ++k) {
            int s = csr_src[k];                 // scalar load (k wave-uniform)
            float a = b2f(csr_attr[k]);         // broadcast load
            float xs0 = ldf<F32>(x, 2 * s), xs1 = ldf<F32>(x, 2 * s + 1);
            float zA = fmaf(xs0, wlaA, fmaf(xs1, wlbA, fmaf(a, weA, cA)));
            float zB = fmaf(xs0, wlaB, fmaf(xs1, wlbB, fmaf(a, weB, cB)));
            float pabs = fmaf(fabsf(zA), aa4A, fabsf(zB) * aa4B);
            pabs = red16(pabs);                 // per-head sum over 32 channels
            float p = fmaf(xs0, P0, fmaf(xs1, P1, fmaf(a, Pw, Kn))) + pabs;
            p = sclamp(p, 60.f);
            float e = __expf(p);                // no max-subtraction: |logit|<=60
            S += e;
            Sx0 = fmaf(e, xs0, Sx0);
            Sx1 = fmaf(e, xs1, Sx1);
        }
        float inv = 1.0f / (S + 1e-16f);
        float R = S * inv, U0 = Sx0 * inv, U1 = Sx1 * inv;   // R=sum(alpha): 0 for isolated nodes
        float outA = fmaf(U0, wlaA, fmaf(U1, wlbA, R * blA));
        float outB = fmaf(U0, wlaB, fmaf(U1, wlbB, R * blB));
        // head mean: lanes {q, q+16, q+32, q+48} hold the 4 heads of channel q
        outA += __shfl_xor(outA, 16); outA += __shfl_xor(outA, 32);
        outB += __shfl_xor(outB, 16); outB += __shfl_xor(outB, 32);
        float valA = fmaf(0.25f, outA, biasA);
        float valB = fmaf(0.25f, outB, biasB);
        // LayerNorm over 32 channels
        float mu = red16(valA + valB) * (1.f / 32.f);
        float dA = valA - mu, dB = valB - mu;
        float var = red16(dA * dA + dB * dB) * (1.f / 32.f);
        float rs = rsqrtf(var + LN_EPS);
        float yA = fmaf(dA * rs, gA, beA);
        float yB = fmaf(dB * rs, gB, beB);
        float hA = yA > 0.f ? yA : expm1f(yA);   // ELU
        float hB = yB > 0.f ? yB : expm1f(yB);
        if (lane < 16) {
            hout[n * 32 + q]      = f2b(hA);
            hout[n * 32 + 16 + q] = f2b(hB);
        }
    }
}

__global__ __launch_bounds__(256) void agg1_kernel(
    const int* __restrict__ flags,
    const int* __restrict__ rowptr, const int* __restrict__ csr_src,
    const bf16* __restrict__ csr_attr, const void* __restrict__ x,
    const void* W1l, const void* b1l, const void* W1r, const void* b1r,
    const void* We1, const void* att1, const void* bias1, const void* g1v, const void* beta1,
    bf16* __restrict__ hout, int N) {
    if (flags[1]) agg1_body<1>(rowptr, csr_src, csr_attr, x, W1l, b1l, W1r, b1r,
                               We1, att1, bias1, g1v, beta1, hout, N);
    else          agg1_body<0>(rowptr, csr_src, csr_attr, x, W1l, b1l, W1r, b1r,
                               We1, att1, bias1, g1v, beta1, hout, N);
}

// ---------------- Layer-2 node transform, in-place over hbuf ----------------

template<int F32>
__device__ void node2_body(bf16* __restrict__ hbuf, float* wl, float* wr,
                           const void* W2l, const void* b2l, const void* W2r, const void* b2r,
                           int N) {
    __shared__ float bl[16], br[16];
    int tid = threadIdx.x;
    for (int i = tid; i < 512; i += 256) { wl[i] = ldf<F32>(W2l, i); wr[i] = ldf<F32>(W2r, i); }
    if (tid < 16) { bl[tid] = ldf<F32>(b2l, tid); br[tid] = ldf<F32>(b2r, tid); }
    __syncthreads();
    int n = blockIdx.x * blockDim.x + tid;
    if (n >= N) return;
    float hv[32];
    #pragma unroll
    for (int c = 0; c < 32; ++c) hv[c] = b2f(hbuf[n * 32 + c]);
    float accl[16], accr[16];
    #pragma unroll
    for (int o = 0; o < 16; ++o) { accl[o] = bl[o]; accr[o] = br[o]; }
    #pragma unroll
    for (int c = 0; c < 32; ++c) {
        #pragma unroll
        for (int o = 0; o < 16; ++o) {
            accl[o] = fmaf(hv[c], wl[c * 16 + o], accl[o]);
            accr[o] = fmaf(hv[c], wr[c * 16 + o], accr[o]);
        }
    }
    #pragma unroll
    for (int o = 0; o < 16; ++o) {
        hbuf[n * 32 + o]      = f2b(accl[o]);   // h2l
        hbuf[n * 32 + 16 + o] = f2b(accr[o]);   // h2r
    }
}

__global__ __launch_bounds__(256) void node2_kernel(
    const int* __restrict__ flags, bf16* __restrict__ hbuf,
    const void* W2l, const void* b2l, const void* W2r, const void* b2r, int N) {
    __shared__ float wl[512], wr[512];
    if (flags[1]) node2_body<1>(hbuf, wl, wr, W2l, b2l, W2r, b2r, N);
    else          node2_body<0>(hbuf, wl, wr, W2l, b2l, W2r, b2r, N);
}

// ---------------- Layer-2 aggregation: 4 sub-groups of 16 lanes ----------------

template<int F32>
__device__ void agg2_body(
    const int* __restrict__ rowptr, const int* __restrict__ csr_src,
    const bf16* __restrict__ csr_attr, const bf16* __restrict__ h2,
    const void* We2, const void* att2, const void* bias2, const void* g2v, const void* beta2,
    void* __restrict__ out, int N) {
    int w0 = __builtin_amdgcn_readfirstlane((blockIdx.x * blockDim.x + threadIdx.x) >> 6);
    int NW = (gridDim.x * blockDim.x) >> 6;
    int lane = threadIdx.x & 63;
    int g = lane >> 4, t = lane & 15;

    float we = ldf<F32>(We2, t), at = ldf<F32>(att2, t);
    float bia = ldf<F32>(bias2, t), gg = ldf<F32>(g2v, t), bb = ldf<F32>(beta2, t);

    for (int n = w0; n < N; n += NW) {
        int beg = rowptr[n], end = rowptr[n + 1];
        float xr = b2f(h2[n * 32 + 16 + t]);   // h2r

        float S = 0.f, A = 0.f;
        for (int k = beg + g; k < end; k += 4) {
            int s = csr_src[k];
            float a = b2f(csr_attr[k]);
            float v = b2f(h2[s * 32 + t]);     // h2l
            float m = fmaf(a, we, v + xr);
            m = fmaxf(m, NEG_SLOPE * m);       // LeakyReLU
            float p = red16(m * at);
            p = sclamp(p, 60.f);
            float e = __expf(p);
            S += e;
            A = fmaf(e, v, A);
        }
        S += __shfl_xor(S, 16); S += __shfl_xor(S, 32);
        A += __shfl_xor(A, 16); A += __shfl_xor(A, 32);
        float val = A / (S + 1e-16f) + bia;    // empty node -> 0 + bias

        float mu = red16(val) * (1.f / 16.f);
        float d = val - mu;
        float var = red16(d * d) * (1.f / 16.f);
        float y = fmaf(d * rsqrtf(var + LN_EPS), gg, bb);
        if (lane < 16) {
            if (F32) ((float*)out)[n * 16 + t] = y;
            else     ((bf16*)out)[n * 16 + t] = f2b(y);
        }
    }
}

__global__ __launch_bounds__(256) void agg2_kernel(
    const int* __restrict__ flags,
    const int* __restrict__ rowptr, const int* __restrict__ csr_src,
    const bf16* __restrict__ csr_attr, const bf16* __restrict__ h2,
    const void* We2, const void* att2, const void* bias2, const void* g2v, const void* beta2,
    void* __restrict__ out, int N) {
    if (flags[1]) agg2_body<1>(rowptr, csr_src, csr_attr, h2, We2, att2, bias2, g2v, beta2, out, N);
    else          agg2_body<0>(rowptr, csr_src, csr_attr, h2, We2, att2, bias2, g2v, beta2, out, N);
}

// ---------------- host ----------------

static inline size_t align256(size_t x) { return (x + 255) & ~size_t(255); }

extern "C" void kernel_launch(void* const* d_in, const int* in_sizes, int n_in,
                              void* d_out, int out_size, void* d_ws, size_t ws_size,
                              hipStream_t stream) {
    const void* x     = d_in[0];
    const int*  ei    = (const int*)d_in[1];
    const void* eattr = d_in[2];
    const void* W1l   = d_in[3];
    const void* b1l   = d_in[4];
    const void* W1r   = d_in[5];
    const void* b1r   = d_in[6];
    const void* We1   = d_in[7];
    const void* att1  = d_in[8];
    const void* bias1 = d_in[9];
    const void* g1    = d_in[10];
    const void* beta1 = d_in[11];
    const void* W2l   = d_in[12];
    const void* b2l   = d_in[13];
    const void* W2r   = d_in[14];
    const void* b2r   = d_in[15];
    const void* We2   = d_in[16];
    const void* att2  = d_in[17];
    const void* bias2 = d_in[18];
    const void* g2    = d_in[19];
    const void* beta2 = d_in[20];

    const int N = in_sizes[0] / 2;   // x is (N,2)
    const int E = in_sizes[2];       // edge_attr is (E,1)
    const int B = (N + SCAN_TILE - 1) / SCAN_TILE;   // scan blocks (49 @ N=50000)

    // workspace (~9.7 MB at N=50000, E=1e6)
    char* ws = (char*)d_ws;
    size_t off = 0;
    int* flags     = (int*)(ws + off); off += align256(sizeof(int) * 2);
    int* bsum      = (int*)(ws + off); off += align256(sizeof(int) * 1024);
    int* cnt       = (int*)(ws + off); off += align256(sizeof(int) * (size_t)N);      // doubles as cursor
    int* rowptr    = (int*)(ws + off); off += align256(sizeof(int) * (size_t)(N + 1));
    int* csr_src   = (int*)(ws + off); off += align256(sizeof(int) * (size_t)E);
    bf16* csr_attr = (bf16*)(ws + off); off += align256(sizeof(bf16) * (size_t)E);
    bf16* hbuf     = (bf16*)(ws + off); off += align256(sizeof(bf16) * (size_t)N * 32);

    hipMemsetAsync(cnt, 0, sizeof(int) * (size_t)N, stream);
    detect_kernel<<<1, 64, 0, stream>>>(ei, (const unsigned short*)x, flags);

    int eb = (E + 255) / 256;
    hist_kernel<<<eb, 256, 0, stream>>>(ei, E, N, flags, cnt);

    scan_partial<<<B, 256, 0, stream>>>(cnt, bsum, N);
    scan_bsum<<<1, 1024, 0, stream>>>(bsum, B, rowptr, N);
    scan_final<<<B, 256, 0, stream>>>(cnt, rowptr, bsum, N);

    scatter_kernel<<<eb, 256, 0, stream>>>(ei, eattr, E, N, flags, cnt, csr_src, csr_attr);

    agg1_kernel<<<2048, 256, 0, stream>>>(flags, rowptr, csr_src, csr_attr, x,
                                          W1l, b1l, W1r, b1r, We1, att1, bias1, g1, beta1,
                                          hbuf, N);

    node2_kernel<<<(N + 255) / 256, 256, 0, stream>>>(flags, hbuf, W2l, b2l, W2r, b2r, N);

    agg2_kernel<<<2048, 256, 0, stream>>>(flags, rowptr, csr_src, csr_attr, hbuf,
                                          We2, att2, bias2, g2, beta2, d_out, N);
}

// Round 7
// 296.979 us; speedup vs baseline: 1.7929x; 1.1387x over previous
//
#include <hip/hip_runtime.h>
#include <hip/hip_bf16.h>
#include <math.h>

typedef __hip_bfloat16 bf16;

__device__ __forceinline__ float b2f(bf16 v) { return __bfloat162float(v); }
__device__ __forceinline__ bf16  f2b(float v) { return __float2bfloat16(v); }

template<int F32>
__device__ __forceinline__ float ldf(const void* p, int i) {
    return F32 ? ((const float*)p)[i] : b2f(((const bf16*)p)[i]);
}
// load x[2s], x[2s+1] as one dword (bf16) or dwordx2 (f32)
template<int F32>
__device__ __forceinline__ void ldx(const void* x, int s, float& x0, float& x1) {
    if (F32) { float2 v = ((const float2*)x)[s]; x0 = v.x; x1 = v.y; }
    else {
        unsigned u = ((const unsigned*)x)[s];
        x0 = __uint_as_float((u & 0xFFFFu) << 16);
        x1 = __uint_as_float(u & 0xFFFF0000u);
    }
}
// clamp that also scrubs NaN (fmaxf/fminf pick the non-NaN operand)
__device__ __forceinline__ float sclamp(float v, float lim) {
    return fminf(fmaxf(v, -lim), lim);
}
// VALU-only sum over each 16-lane row: quad_perm xor1, xor2 then row_ror 4, 8
template<int CTRL>
__device__ __forceinline__ float dpp_add(float v) {
    int t = __builtin_amdgcn_update_dpp(0, __float_as_int(v), CTRL, 0xF, 0xF, true);
    return v + __int_as_float(t);
}
__device__ __forceinline__ float red16(float v) {
    v = dpp_add<0xB1>(v);    // quad_perm [1,0,3,2]
    v = dpp_add<0x4E>(v);    // quad_perm [2,3,0,1]
    v = dpp_add<0x124>(v);   // row_ror:4
    v = dpp_add<0x128>(v);   // row_ror:8
    return v;
}

#define NEG_SLOPE 0.2f
#define LN_EPS 1e-5f
#define SCAN_TILE 1024   // elements per scan block (256 thr x 4)

__device__ __forceinline__ int ld_idx(const int* ei, long long pos, int is64, int N) {
    int v = is64 ? ei[2 * pos] : ei[pos];
    return min(max(v, 0), N - 1);
}

// derive is64 locally from the first 8 index values (int64 LE: odd words zero)
__device__ __forceinline__ int calc_is64(const int* ei) {
    int hi = 0, nz = 0;
    #pragma unroll
    for (int i = 0; i < 8; ++i) { hi |= ei[2 * i + 1]; nz |= ei[2 * i]; }
    return (hi == 0 && nz != 0) ? 1 : 0;
}

// ---------------- CSR build (detect folded in) ----------------

__global__ void hist_kernel(const int* __restrict__ ei,
                            const unsigned short* __restrict__ xu,
                            int E, int N, int* __restrict__ flags, int* __restrict__ cnt) {
    int is64 = calc_is64(ei);
    if (blockIdx.x == 0 && threadIdx.x == 0) {
        flags[0] = is64;
        int pl = 0;
        for (int i = 0; i < 32; ++i) {
            unsigned ex = (xu[2 * i] >> 7) & 0xFF;
            if (ex >= 100 && ex <= 140) pl++;
        }
        flags[1] = (pl >= 24) ? 0 : 1;   // 1 = float tensors are fp32
    }
    int e = blockIdx.x * blockDim.x + threadIdx.x;
    if (e >= E) return;
    atomicAdd(&cnt[ld_idx(ei, (long long)E + e, is64, N)], 1);
}

// ---- 2-phase multi-block exclusive scan of cnt -> rowptr + cursor(in place) ----

__global__ __launch_bounds__(256) void scan_partial(const int* __restrict__ cnt,
                                                    int* __restrict__ bsum, int N) {
    __shared__ int wsum[4];
    int b = blockIdx.x, tid = threadIdx.x;
    int base = b * SCAN_TILE + tid * 4;
    int4 v = make_int4(0, 0, 0, 0);
    if (base + 3 < N) v = *(const int4*)(cnt + base);
    else {
        if (base + 0 < N) v.x = cnt[base + 0];
        if (base + 1 < N) v.y = cnt[base + 1];
        if (base + 2 < N) v.z = cnt[base + 2];
    }
    int s = v.x + v.y + v.z + v.w;
    #pragma unroll
    for (int off = 1; off < 64; off <<= 1) s += __shfl_xor(s, off);
    if ((tid & 63) == 0) wsum[tid >> 6] = s;
    __syncthreads();
    if (tid == 0) bsum[b] = wsum[0] + wsum[1] + wsum[2] + wsum[3];
}

// each block: scan bsum (B<=256) locally, then local tile scan + write rowptr/cursor
__global__ __launch_bounds__(256) void scan_final(int* __restrict__ cnt, int* __restrict__ rowptr,
                                                  const int* __restrict__ bsum, int N, int B) {
    __shared__ int tsum[256];
    __shared__ int bpre[256];
    int b = blockIdx.x, tid = threadIdx.x;
    bpre[tid] = (tid < B) ? bsum[tid] : 0;
    int base = b * SCAN_TILE + tid * 4;
    int4 v = make_int4(0, 0, 0, 0);
    if (base + 3 < N) v = *(const int4*)(cnt + base);
    else {
        if (base + 0 < N) v.x = cnt[base + 0];
        if (base + 1 < N) v.y = cnt[base + 1];
        if (base + 2 < N) v.z = cnt[base + 2];
    }
    tsum[tid] = v.x + v.y + v.z + v.w;
    __syncthreads();
    for (int off = 1; off < 256; off <<= 1) {
        int t = (tid >= off) ? tsum[tid - off] : 0;
        int u = (tid >= off) ? bpre[tid - off] : 0;
        __syncthreads();
        tsum[tid] += t;
        bpre[tid] += u;
        __syncthreads();
    }
    int blockpre = (b == 0) ? 0 : bpre[b - 1];
    int o0 = blockpre + ((tid == 0) ? 0 : tsum[tid - 1]);
    int o1 = o0 + v.x, o2 = o1 + v.y, o3 = o2 + v.z;
    if (base + 3 < N) {
        int4 o = make_int4(o0, o1, o2, o3);
        *(int4*)(rowptr + base) = o;
        *(int4*)(cnt + base) = o;          // cursor
    } else {
        if (base + 0 < N) { rowptr[base + 0] = o0; cnt[base + 0] = o0; }
        if (base + 1 < N) { rowptr[base + 1] = o1; cnt[base + 1] = o1; }
        if (base + 2 < N) { rowptr[base + 2] = o2; cnt[base + 2] = o2; }
    }
    if (b == 0 && tid == 255) rowptr[N] = bpre[255];   // total (zero-padded inclusive)
}

template<int F32>
__device__ void scatter_body(const int* __restrict__ ei, const void* __restrict__ attr,
                             int E, int N, int is64, int* __restrict__ cursor,
                             int* __restrict__ csr_src, bf16* __restrict__ csr_attr) {
    int e = blockIdx.x * blockDim.x + threadIdx.x;
    if (e >= E) return;
    int d = ld_idx(ei, (long long)E + e, is64, N);
    int s = ld_idx(ei, (long long)e, is64, N);
    int pos = atomicAdd(&cursor[d], 1);
    csr_src[pos] = s;
    csr_attr[pos] = f2b(ldf<F32>(attr, e));
}

__global__ void scatter_kernel(const int* __restrict__ ei, const void* __restrict__ attr,
                               int E, int N, const int* __restrict__ flags,
                               int* __restrict__ cursor,
                               int* __restrict__ csr_src, bf16* __restrict__ csr_attr) {
    if (flags[1]) scatter_body<1>(ei, attr, E, N, flags[0], cursor, csr_src, csr_attr);
    else          scatter_body<0>(ei, attr, E, N, flags[0], cursor, csr_src, csr_attr);
}

// ---------------- Layer-1 aggregation ----------------
// Head-major: lane = h*16+q. att.LeakyReLU(z) = 0.6 att.z (3 FMA via per-head dots)
// + 0.4 att.|z| (per-channel, DPP row-reduce). Value path affine in (xs0,xs1,1).
// K-loop 2x-batched for load-level parallelism.

template<int F32>
__device__ void agg1_body(
    const int* __restrict__ rowptr, const int* __restrict__ csr_src,
    const bf16* __restrict__ csr_attr, const void* __restrict__ x,
    const void* W1l, const void* b1l, const void* W1r, const void* b1r,
    const void* We1, const void* att1, const void* bias1, const void* g1v, const void* beta1,
    bf16* __restrict__ hout, int N) {
    int w0 = __builtin_amdgcn_readfirstlane((blockIdx.x * blockDim.x + threadIdx.x) >> 6);
    int NW = (gridDim.x * blockDim.x) >> 6;
    int lane = threadIdx.x & 63;
    int h = lane >> 4, q = lane & 15;
    int ja = h * 32 + q, jb = ja + 16;

    float wlaA = ldf<F32>(W1l, ja),      wlaB = ldf<F32>(W1l, jb);
    float wlbA = ldf<F32>(W1l, 128 + ja), wlbB = ldf<F32>(W1l, 128 + jb);
    float wraA = ldf<F32>(W1r, ja),      wraB = ldf<F32>(W1r, jb);
    float wrbA = ldf<F32>(W1r, 128 + ja), wrbB = ldf<F32>(W1r, 128 + jb);
    float blA = ldf<F32>(b1l, ja), blB = ldf<F32>(b1l, jb);
    float brA = ldf<F32>(b1r, ja), brB = ldf<F32>(b1r, jb);
    float weA = ldf<F32>(We1, ja), weB = ldf<F32>(We1, jb);
    float atA = ldf<F32>(att1, ja), atB = ldf<F32>(att1, jb);
    float aa4A = 0.4f * atA, aa4B = 0.4f * atB;
    float blbrA = blA + brA, blbrB = blB + brB;
    float P0 = 0.6f * red16(atA * wlaA + atB * wlaB);
    float P1 = 0.6f * red16(atA * wlbA + atB * wlbB);
    float Pw = 0.6f * red16(atA * weA + atB * weB);
    float Q0 = 0.6f * red16(atA * wraA + atB * wraB);
    float Q1 = 0.6f * red16(atA * wrbA + atB * wrbB);
    float Qc = 0.6f * red16(atA * blbrA + atB * blbrB);
    float biasA = ldf<F32>(bias1, q), biasB = ldf<F32>(bias1, q + 16);
    float gA = ldf<F32>(g1v, q), gB = ldf<F32>(g1v, q + 16);
    float beA = ldf<F32>(beta1, q), beB = ldf<F32>(beta1, q + 16);

    for (int n = w0; n < N; n += NW) {
        int beg = rowptr[n], end = rowptr[n + 1];
        float xd0, xd1;
        ldx<F32>(x, n, xd0, xd1);
        float cA = fmaf(xd0, wraA, fmaf(xd1, wrbA, blbrA));
        float cB = fmaf(xd0, wraB, fmaf(xd1, wrbB, blbrB));
        float Kn = fmaf(xd0, Q0, fmaf(xd1, Q1, Qc));
        float S = 0.f, Sx0 = 0.f, Sx1 = 0.f;

        auto edge = [&](float xs0, float xs1, float a) {
            float zA = fmaf(xs0, wlaA, fmaf(xs1, wlbA, fmaf(a, weA, cA)));
            float zB = fmaf(xs0, wlaB, fmaf(xs1, wlbB, fmaf(a, weB, cB)));
            float pabs = red16(fmaf(fabsf(zA), aa4A, fabsf(zB) * aa4B));
            float p = sclamp(fmaf(xs0, P0, fmaf(xs1, P1, fmaf(a, Pw, Kn))) + pabs, 60.f);
            float e = __expf(p);
            S += e;
            Sx0 = fmaf(e, xs0, Sx0);
            Sx1 = fmaf(e, xs1, Sx1);
        };

        int k = beg;
        for (; k + 2 <= end; k += 2) {        // 2x batch: both gathers in flight together
            int s0 = csr_src[k], s1 = csr_src[k + 1];
            float a0 = b2f(csr_attr[k]), a1 = b2f(csr_attr[k + 1]);
            float u0, u1, v0x, v1x;
            ldx<F32>(x, s0, u0, u1);
            ldx<F32>(x, s1, v0x, v1x);
            edge(u0, u1, a0);
            edge(v0x, v1x, a1);
        }
        if (k < end) {
            int s0 = csr_src[k];
            float a0 = b2f(csr_attr[k]);
            float u0, u1;
            ldx<F32>(x, s0, u0, u1);
            edge(u0, u1, a0);
        }

        float inv = 1.0f / (S + 1e-16f);
        float R = S * inv, U0 = Sx0 * inv, U1 = Sx1 * inv;   // R=0 for isolated nodes
        float outA = fmaf(U0, wlaA, fmaf(U1, wlbA, R * blA));
        float outB = fmaf(U0, wlaB, fmaf(U1, wlbB, R * blB));
        // head mean: lanes {q, q+16, q+32, q+48} hold the 4 heads of channel q
        outA += __shfl_xor(outA, 16); outA += __shfl_xor(outA, 32);
        outB += __shfl_xor(outB, 16); outB += __shfl_xor(outB, 32);
        float valA = fmaf(0.25f, outA, biasA);
        float valB = fmaf(0.25f, outB, biasB);
        // LayerNorm over 32 channels
        float mu = red16(valA + valB) * (1.f / 32.f);
        float dA = valA - mu, dB = valB - mu;
        float var = red16(dA * dA + dB * dB) * (1.f / 32.f);
        float rs = rsqrtf(var + LN_EPS);
        float yA = fmaf(dA * rs, gA, beA);
        float yB = fmaf(dB * rs, gB, beB);
        float hA = yA > 0.f ? yA : expm1f(yA);   // ELU
        float hB = yB > 0.f ? yB : expm1f(yB);
        if (lane < 16) {
            hout[n * 32 + q]      = f2b(hA);
            hout[n * 32 + 16 + q] = f2b(hB);
        }
    }
}

__global__ __launch_bounds__(256) void agg1_kernel(
    const int* __restrict__ flags,
    const int* __restrict__ rowptr, const int* __restrict__ csr_src,
    const bf16* __restrict__ csr_attr, const void* __restrict__ x,
    const void* W1l, const void* b1l, const void* W1r, const void* b1r,
    const void* We1, const void* att1, const void* bias1, const void* g1v, const void* beta1,
    bf16* __restrict__ hout, int N) {
    if (flags[1]) agg1_body<1>(rowptr, csr_src, csr_attr, x, W1l, b1l, W1r, b1r,
                               We1, att1, bias1, g1v, beta1, hout, N);
    else          agg1_body<0>(rowptr, csr_src, csr_attr, x, W1l, b1l, W1r, b1r,
                               We1, att1, bias1, g1v, beta1, hout, N);
}

// ---------------- Layer-2 node transform, in-place over hbuf ----------------

template<int F32>
__device__ void node2_body(bf16* __restrict__ hbuf, float* wl, float* wr,
                           const void* W2l, const void* b2l, const void* W2r, const void* b2r,
                           int N) {
    __shared__ float bl[16], br[16];
    int tid = threadIdx.x;
    for (int i = tid; i < 512; i += 256) { wl[i] = ldf<F32>(W2l, i); wr[i] = ldf<F32>(W2r, i); }
    if (tid < 16) { bl[tid] = ldf<F32>(b2l, tid); br[tid] = ldf<F32>(b2r, tid); }
    __syncthreads();
    int n = blockIdx.x * blockDim.x + tid;
    if (n >= N) return;
    float hv[32];
    #pragma unroll
    for (int c = 0; c < 32; ++c) hv[c] = b2f(hbuf[n * 32 + c]);
    float accl[16], accr[16];
    #pragma unroll
    for (int o = 0; o < 16; ++o) { accl[o] = bl[o]; accr[o] = br[o]; }
    #pragma unroll
    for (int c = 0; c < 32; ++c) {
        #pragma unroll
        for (int o = 0; o < 16; ++o) {
            accl[o] = fmaf(hv[c], wl[c * 16 + o], accl[o]);
            accr[o] = fmaf(hv[c], wr[c * 16 + o], accr[o]);
        }
    }
    #pragma unroll
    for (int o = 0; o < 16; ++o) {
        hbuf[n * 32 + o]      = f2b(accl[o]);   // h2l
        hbuf[n * 32 + 16 + o] = f2b(accr[o]);   // h2r
    }
}

__global__ __launch_bounds__(256) void node2_kernel(
    const int* __restrict__ flags, bf16* __restrict__ hbuf,
    const void* W2l, const void* b2l, const void* W2r, const void* b2r, int N) {
    __shared__ float wl[512], wr[512];
    if (flags[1]) node2_body<1>(hbuf, wl, wr, W2l, b2l, W2r, b2r, N);
    else          node2_body<0>(hbuf, wl, wr, W2l, b2l, W2r, b2r, N);
}

// ---------------- Layer-2 aggregation: 4 sub-groups of 16 lanes ----------------

template<int F32>
__device__ void agg2_body(
    const int* __restrict__ rowptr, const int* __restrict__ csr_src,
    const bf16* __restrict__ csr_attr, const bf16* __restrict__ h2,
    const void* We2, const void* att2, const void* bias2, const void* g2v, const void* beta2,
    void* __restrict__ out, int N) {
    int w0 = __builtin_amdgcn_readfirstlane((blockIdx.x * blockDim.x + threadIdx.x) >> 6);
    int NW = (gridDim.x * blockDim.x) >> 6;
    int lane = threadIdx.x & 63;
    int g = lane >> 4, t = lane & 15;

    float we = ldf<F32>(We2, t), at = ldf<F32>(att2, t);
    float bia = ldf<F32>(bias2, t), gg = ldf<F32>(g2v, t), bb = ldf<F32>(beta2, t);

    for (int n = w0; n < N; n += NW) {
        int beg = rowptr[n], end = rowptr[n + 1];
        float xr = b2f(h2[n * 32 + 16 + t]);   // h2r

        float S = 0.f, A = 0.f;
        auto edge = [&](float v, float a) {
            float m = fmaf(a, we, v + xr);
            m = fmaxf(m, NEG_SLOPE * m);       // LeakyReLU
            float p = sclamp(red16(m * at), 60.f);
            float e = __expf(p);
            S += e;
            A = fmaf(e, v, A);
        };
        int k = beg + g;
        for (; k + 4 < end; k += 8) {          // 2x batch per sub-group
            int s0 = csr_src[k], s1 = csr_src[k + 4];
            float a0 = b2f(csr_attr[k]), a1 = b2f(csr_attr[k + 4]);
            float v0 = b2f(h2[s0 * 32 + t]);
            float v1 = b2f(h2[s1 * 32 + t]);
            edge(v0, a0);
            edge(v1, a1);
        }
        if (k < end) {
            int s0 = csr_src[k];
            float a0 = b2f(csr_attr[k]);
            edge(b2f(h2[s0 * 32 + t]), a0);
        }
        S += __shfl_xor(S, 16); S += __shfl_xor(S, 32);
        A += __shfl_xor(A, 16); A += __shfl_xor(A, 32);
        float val = A / (S + 1e-16f) + bia;    // empty node -> 0 + bias

        float mu = red16(val) * (1.f / 16.f);
        float d = val - mu;
        float var = red16(d * d) * (1.f / 16.f);
        float y = fmaf(d * rsqrtf(var + LN_EPS), gg, bb);
        if (lane < 16) {
            if (F32) ((float*)out)[n * 16 + t] = y;
            else     ((bf16*)out)[n * 16 + t] = f2b(y);
        }
    }
}

__global__ __launch_bounds__(256) void agg2_kernel(
    const int* __restrict__ flags,
    const int* __restrict__ rowptr, const int* __restrict__ csr_src,
    const bf16* __restrict__ csr_attr, const bf16* __restrict__ h2,
    const void* We2, const void* att2, const void* bias2, const void* g2v, const void* beta2,
    void* __restrict__ out, int N) {
    if (flags[1]) agg2_body<1>(rowptr, csr_src, csr_attr, h2, We2, att2, bias2, g2v, beta2, out, N);
    else          agg2_body<0>(rowptr, csr_src, csr_attr, h2, We2, att2, bias2, g2v, beta2, out, N);
}

// ---------------- host ----------------

static inline size_t align256(size_t x) { return (x + 255) & ~size_t(255); }

extern "C" void kernel_launch(void* const* d_in, const int* in_sizes, int n_in,
                              void* d_out, int out_size, void* d_ws, size_t ws_size,
                              hipStream_t stream) {
    const void* x     = d_in[0];
    const int*  ei    = (const int*)d_in[1];
    const void* eattr = d_in[2];
    const void* W1l   = d_in[3];
    const void* b1l   = d_in[4];
    const void* W1r   = d_in[5];
    const void* b1r   = d_in[6];
    const void* We1   = d_in[7];
    const void* att1  = d_in[8];
    const void* bias1 = d_in[9];
    const void* g1    = d_in[10];
    const void* beta1 = d_in[11];
    const void* W2l   = d_in[12];
    const void* b2l   = d_in[13];
    const void* W2r   = d_in[14];
    const void* b2r   = d_in[15];
    const void* We2   = d_in[16];
    const void* att2  = d_in[17];
    const void* bias2 = d_in[18];
    const void* g2    = d_in[19];
    const void* beta2 = d_in[20];

    const int N = in_sizes[0] / 2;   // x is (N,2)
    const int E = in_sizes[2];       // edge_attr is (E,1)
    const int B = (N + SCAN_TILE - 1) / SCAN_TILE;   // 49 @ N=50000 (<=256 supported)

    // workspace (~9.7 MB at N=50000, E=1e6)
    char* ws = (char*)d_ws;
    size_t off = 0;
    int* flags     = (int*)(ws + off); off += align256(sizeof(int) * 2);
    int* bsum      = (int*)(ws + off); off += align256(sizeof(int) * 1024);
    int* cnt       = (int*)(ws + off); off += align256(sizeof(int) * (size_t)N);      // doubles as cursor
    int* rowptr    = (int*)(ws + off); off += align256(sizeof(int) * (size_t)(N + 1));
    int* csr_src   = (int*)(ws + off); off += align256(sizeof(int) * (size_t)E);
    bf16* csr_attr = (bf16*)(ws + off); off += align256(sizeof(bf16) * (size_t)E);
    bf16* hbuf     = (bf16*)(ws + off); off += align256(sizeof(bf16) * (size_t)N * 32);

    hipMemsetAsync(cnt, 0, sizeof(int) * (size_t)N, stream);

    int eb = (E + 255) / 256;
    hist_kernel<<<eb, 256, 0, stream>>>(ei, (const unsigned short*)x, E, N, flags, cnt);

    scan_partial<<<B, 256, 0, stream>>>(cnt, bsum, N);
    scan_final<<<B, 256, 0, stream>>>(cnt, rowptr, bsum, N, B);

    scatter_kernel<<<eb, 256, 0, stream>>>(ei, eattr, E, N, flags, cnt, csr_src, csr_attr);

    agg1_kernel<<<2048, 256, 0, stream>>>(flags, rowptr, csr_src, csr_attr, x,
                                          W1l, b1l, W1r, b1r, We1, att1, bias1, g1, beta1,
                                          hbuf, N);

    node2_kernel<<<(N + 255) / 256, 256, 0, stream>>>(flags, hbuf, W2l, b2l, W2r, b2r, N);

    agg2_kernel<<<2048, 256, 0, stream>>>(flags, rowptr, csr_src, csr_attr, hbuf,
                                          We2, att2, bias2, g2, beta2, d_out, N);
}

// Round 8
// 295.023 us; speedup vs baseline: 1.8048x; 1.0066x over previous
//
#include <hip/hip_runtime.h>
#include <hip/hip_bf16.h>
#include <math.h>

typedef __hip_bfloat16 bf16;

__device__ __forceinline__ float b2f(bf16 v) { return __bfloat162float(v); }
__device__ __forceinline__ bf16  f2b(float v) { return __float2bfloat16(v); }

template<int F32>
__device__ __forceinline__ float ldf(const void* p, int i) {
    return F32 ? ((const float*)p)[i] : b2f(((const bf16*)p)[i]);
}
// load x[2s], x[2s+1] as one dword (bf16) or dwordx2 (f32)
template<int F32>
__device__ __forceinline__ void ldx(const void* x, int s, float& x0, float& x1) {
    if (F32) { float2 v = ((const float2*)x)[s]; x0 = v.x; x1 = v.y; }
    else {
        unsigned u = ((const unsigned*)x)[s];
        x0 = __uint_as_float((u & 0xFFFFu) << 16);
        x1 = __uint_as_float(u & 0xFFFF0000u);
    }
}
// f32 -> bf16 bits (RNE), returned in HIGH 16 bits (so uint_as_float works directly)
__device__ __forceinline__ unsigned f2b_hi(float f) {
    unsigned u = __float_as_uint(f);
    u += 0x7FFFu + ((u >> 16) & 1u);
    return u & 0xFFFF0000u;
}
// CSR record: P4 -> 4B (attr_hi16 | src16, needs N<=65536); else 8B (src, attr_f32bits)
template<int P4>
__device__ __forceinline__ void ldrec(const void* csr, int k, int& s, float& a) {
    if (P4) {
        unsigned u = ((const unsigned*)csr)[k];
        s = (int)(u & 0xFFFFu);
        a = __uint_as_float(u & 0xFFFF0000u);
    } else {
        uint2 r = ((const uint2*)csr)[k];
        s = (int)r.x;
        a = __uint_as_float(r.y);
    }
}
// clamp that also scrubs NaN (fmaxf/fminf pick the non-NaN operand)
__device__ __forceinline__ float sclamp(float v, float lim) {
    return fminf(fmaxf(v, -lim), lim);
}
// VALU-only sum over each 16-lane row: quad_perm xor1, xor2 then row_ror 4, 8
template<int CTRL>
__device__ __forceinline__ float dpp_add(float v) {
    int t = __builtin_amdgcn_update_dpp(0, __float_as_int(v), CTRL, 0xF, 0xF, true);
    return v + __int_as_float(t);
}
__device__ __forceinline__ float red16(float v) {
    v = dpp_add<0xB1>(v);    // quad_perm [1,0,3,2]
    v = dpp_add<0x4E>(v);    // quad_perm [2,3,0,1]
    v = dpp_add<0x124>(v);   // row_ror:4
    v = dpp_add<0x128>(v);   // row_ror:8
    return v;
}

#define NEG_SLOPE 0.2f
#define LN_EPS 1e-5f
#define SCAN_TILE 1024   // elements per scan block (256 thr x 4)

__device__ __forceinline__ int ld_idx(const int* ei, long long pos, int is64, int N) {
    int v = is64 ? ei[2 * pos] : ei[pos];
    return min(max(v, 0), N - 1);
}

// derive is64 locally from the first 8 index values (int64 LE: odd words zero)
__device__ __forceinline__ int calc_is64(const int* ei) {
    int hi = 0, nz = 0;
    #pragma unroll
    for (int i = 0; i < 8; ++i) { hi |= ei[2 * i + 1]; nz |= ei[2 * i]; }
    return (hi == 0 && nz != 0) ? 1 : 0;
}

// ---------------- CSR build (detect folded in) ----------------

__global__ void hist_kernel(const int* __restrict__ ei,
                            const unsigned short* __restrict__ xu,
                            int E, int N, int* __restrict__ flags, int* __restrict__ cnt) {
    int is64 = calc_is64(ei);
    if (blockIdx.x == 0 && threadIdx.x == 0) {
        flags[0] = is64;
        int pl = 0;
        for (int i = 0; i < 32; ++i) {
            unsigned ex = (xu[2 * i] >> 7) & 0xFF;
            if (ex >= 100 && ex <= 140) pl++;
        }
        flags[1] = (pl >= 24) ? 0 : 1;   // 1 = float tensors are fp32
    }
    int e = blockIdx.x * blockDim.x + threadIdx.x;
    if (e >= E) return;
    atomicAdd(&cnt[ld_idx(ei, (long long)E + e, is64, N)], 1);
}

// ---- 2-phase multi-block exclusive scan of cnt -> rowptr + cursor(in place) ----

__global__ __launch_bounds__(256) void scan_partial(const int* __restrict__ cnt,
                                                    int* __restrict__ bsum, int N) {
    __shared__ int wsum[4];
    int b = blockIdx.x, tid = threadIdx.x;
    int base = b * SCAN_TILE + tid * 4;
    int4 v = make_int4(0, 0, 0, 0);
    if (base + 3 < N) v = *(const int4*)(cnt + base);
    else {
        if (base + 0 < N) v.x = cnt[base + 0];
        if (base + 1 < N) v.y = cnt[base + 1];
        if (base + 2 < N) v.z = cnt[base + 2];
    }
    int s = v.x + v.y + v.z + v.w;
    #pragma unroll
    for (int off = 1; off < 64; off <<= 1) s += __shfl_xor(s, off);
    if ((tid & 63) == 0) wsum[tid >> 6] = s;
    __syncthreads();
    if (tid == 0) bsum[b] = wsum[0] + wsum[1] + wsum[2] + wsum[3];
}

// each block: scan bsum (B<=256) locally, then local tile scan + write rowptr/cursor
__global__ __launch_bounds__(256) void scan_final(int* __restrict__ cnt, int* __restrict__ rowptr,
                                                  const int* __restrict__ bsum, int N, int B) {
    __shared__ int tsum[256];
    __shared__ int bpre[256];
    int b = blockIdx.x, tid = threadIdx.x;
    bpre[tid] = (tid < B) ? bsum[tid] : 0;
    int base = b * SCAN_TILE + tid * 4;
    int4 v = make_int4(0, 0, 0, 0);
    if (base + 3 < N) v = *(const int4*)(cnt + base);
    else {
        if (base + 0 < N) v.x = cnt[base + 0];
        if (base + 1 < N) v.y = cnt[base + 1];
        if (base + 2 < N) v.z = cnt[base + 2];
    }
    tsum[tid] = v.x + v.y + v.z + v.w;
    __syncthreads();
    for (int off = 1; off < 256; off <<= 1) {
        int t = (tid >= off) ? tsum[tid - off] : 0;
        int u = (tid >= off) ? bpre[tid - off] : 0;
        __syncthreads();
        tsum[tid] += t;
        bpre[tid] += u;
        __syncthreads();
    }
    int blockpre = (b == 0) ? 0 : bpre[b - 1];
    int o0 = blockpre + ((tid == 0) ? 0 : tsum[tid - 1]);
    int o1 = o0 + v.x, o2 = o1 + v.y, o3 = o2 + v.z;
    if (base + 3 < N) {
        int4 o = make_int4(o0, o1, o2, o3);
        *(int4*)(rowptr + base) = o;
        *(int4*)(cnt + base) = o;          // cursor
    } else {
        if (base + 0 < N) { rowptr[base + 0] = o0; cnt[base + 0] = o0; }
        if (base + 1 < N) { rowptr[base + 1] = o1; cnt[base + 1] = o1; }
        if (base + 2 < N) { rowptr[base + 2] = o2; cnt[base + 2] = o2; }
    }
    if (b == 0 && tid == 255) rowptr[N] = bpre[255];   // total (zero-padded inclusive)
}

// ---------------- scatter: one packed record per edge ----------------

template<int F32, int P4>
__device__ void scatter_body(const int* __restrict__ ei, const void* __restrict__ attr,
                             int E, int N, int is64, int* __restrict__ cursor,
                             void* __restrict__ csr) {
    int e = blockIdx.x * blockDim.x + threadIdx.x;
    if (e >= E) return;
    int d = ld_idx(ei, (long long)E + e, is64, N);
    int s = ld_idx(ei, (long long)e, is64, N);
    float av = ldf<F32>(attr, e);
    int pos = atomicAdd(&cursor[d], 1);
    if (P4) ((unsigned*)csr)[pos] = f2b_hi(av) | (unsigned)s;
    else    ((uint2*)csr)[pos] = make_uint2((unsigned)s, __float_as_uint(av));
}

template<int P4>
__global__ void scatter_kernel(const int* __restrict__ ei, const void* __restrict__ attr,
                               int E, int N, const int* __restrict__ flags,
                               int* __restrict__ cursor, void* __restrict__ csr) {
    if (flags[1]) scatter_body<1, P4>(ei, attr, E, N, flags[0], cursor, csr);
    else          scatter_body<0, P4>(ei, attr, E, N, flags[0], cursor, csr);
}

// ---------------- Layer-1 aggregation ----------------
// Head-major: lane = h*16+q. att.LeakyReLU(z) = 0.6 att.z (3 FMA via per-head dots)
// + 0.4 att.|z| (per-channel, DPP row-reduce). Value path affine in (xs0,xs1,1).
// K-loop 4x-batched; one wave-uniform 4B record load per edge.

template<int F32, int P4>
__device__ void agg1_body(
    const int* __restrict__ rowptr, const void* __restrict__ csr,
    const void* __restrict__ x,
    const void* W1l, const void* b1l, const void* W1r, const void* b1r,
    const void* We1, const void* att1, const void* bias1, const void* g1v, const void* beta1,
    bf16* __restrict__ hout, int N) {
    int w0 = __builtin_amdgcn_readfirstlane((blockIdx.x * blockDim.x + threadIdx.x) >> 6);
    int NW = (gridDim.x * blockDim.x) >> 6;
    int lane = threadIdx.x & 63;
    int h = lane >> 4, q = lane & 15;
    int ja = h * 32 + q, jb = ja + 16;

    float wlaA = ldf<F32>(W1l, ja),      wlaB = ldf<F32>(W1l, jb);
    float wlbA = ldf<F32>(W1l, 128 + ja), wlbB = ldf<F32>(W1l, 128 + jb);
    float wraA = ldf<F32>(W1r, ja),      wraB = ldf<F32>(W1r, jb);
    float wrbA = ldf<F32>(W1r, 128 + ja), wrbB = ldf<F32>(W1r, 128 + jb);
    float blA = ldf<F32>(b1l, ja), blB = ldf<F32>(b1l, jb);
    float brA = ldf<F32>(b1r, ja), brB = ldf<F32>(b1r, jb);
    float weA = ldf<F32>(We1, ja), weB = ldf<F32>(We1, jb);
    float atA = ldf<F32>(att1, ja), atB = ldf<F32>(att1, jb);
    float aa4A = 0.4f * atA, aa4B = 0.4f * atB;
    float blbrA = blA + brA, blbrB = blB + brB;
    float P0 = 0.6f * red16(atA * wlaA + atB * wlaB);
    float P1 = 0.6f * red16(atA * wlbA + atB * wlbB);
    float Pw = 0.6f * red16(atA * weA + atB * weB);
    float Q0 = 0.6f * red16(atA * wraA + atB * wraB);
    float Q1 = 0.6f * red16(atA * wrbA + atB * wrbB);
    float Qc = 0.6f * red16(atA * blbrA + atB * blbrB);
    float biasA = ldf<F32>(bias1, q), biasB = ldf<F32>(bias1, q + 16);
    float gA = ldf<F32>(g1v, q), gB = ldf<F32>(g1v, q + 16);
    float beA = ldf<F32>(beta1, q), beB = ldf<F32>(beta1, q + 16);

    for (int n = w0; n < N; n += NW) {
        int beg = rowptr[n], end = rowptr[n + 1];
        float xd0, xd1;
        ldx<F32>(x, n, xd0, xd1);
        float cA = fmaf(xd0, wraA, fmaf(xd1, wrbA, blbrA));
        float cB = fmaf(xd0, wraB, fmaf(xd1, wrbB, blbrB));
        float Kn = fmaf(xd0, Q0, fmaf(xd1, Q1, Qc));
        float S = 0.f, Sx0 = 0.f, Sx1 = 0.f;

        auto edge = [&](float xs0, float xs1, float a) {
            float zA = fmaf(xs0, wlaA, fmaf(xs1, wlbA, fmaf(a, weA, cA)));
            float zB = fmaf(xs0, wlaB, fmaf(xs1, wlbB, fmaf(a, weB, cB)));
            float pabs = red16(fmaf(fabsf(zA), aa4A, fabsf(zB) * aa4B));
            float p = sclamp(fmaf(xs0, P0, fmaf(xs1, P1, fmaf(a, Pw, Kn))) + pabs, 60.f);
            float e = __expf(p);
            S += e;
            Sx0 = fmaf(e, xs0, Sx0);
            Sx1 = fmaf(e, xs1, Sx1);
        };

        int k = beg;
        for (; k + 4 <= end; k += 4) {        // 4x batch: all gathers issued together
            int s0, s1, s2, s3;
            float a0, a1, a2, a3;
            ldrec<P4>(csr, k, s0, a0);
            ldrec<P4>(csr, k + 1, s1, a1);
            ldrec<P4>(csr, k + 2, s2, a2);
            ldrec<P4>(csr, k + 3, s3, a3);
            float p0, p1, q0, q1, r0, r1, t0, t1;
            ldx<F32>(x, s0, p0, p1);
            ldx<F32>(x, s1, q0, q1);
            ldx<F32>(x, s2, r0, r1);
            ldx<F32>(x, s3, t0, t1);
            edge(p0, p1, a0);
            edge(q0, q1, a1);
            edge(r0, r1, a2);
            edge(t0, t1, a3);
        }
        for (; k < end; ++k) {
            int s0; float a0;
            ldrec<P4>(csr, k, s0, a0);
            float p0, p1;
            ldx<F32>(x, s0, p0, p1);
            edge(p0, p1, a0);
        }

        float inv = 1.0f / (S + 1e-16f);
        float R = S * inv, U0 = Sx0 * inv, U1 = Sx1 * inv;   // R=0 for isolated nodes
        float outA = fmaf(U0, wlaA, fmaf(U1, wlbA, R * blA));
        float outB = fmaf(U0, wlaB, fmaf(U1, wlbB, R * blB));
        // head mean: lanes {q, q+16, q+32, q+48} hold the 4 heads of channel q
        outA += __shfl_xor(outA, 16); outA += __shfl_xor(outA, 32);
        outB += __shfl_xor(outB, 16); outB += __shfl_xor(outB, 32);
        float valA = fmaf(0.25f, outA, biasA);
        float valB = fmaf(0.25f, outB, biasB);
        // LayerNorm over 32 channels
        float mu = red16(valA + valB) * (1.f / 32.f);
        float dA = valA - mu, dB = valB - mu;
        float var = red16(dA * dA + dB * dB) * (1.f / 32.f);
        float rs = rsqrtf(var + LN_EPS);
        float yA = fmaf(dA * rs, gA, beA);
        float yB = fmaf(dB * rs, gB, beB);
        float hA = yA > 0.f ? yA : expm1f(yA);   // ELU
        float hB = yB > 0.f ? yB : expm1f(yB);
        if (lane < 16) {
            hout[n * 32 + q]      = f2b(hA);
            hout[n * 32 + 16 + q] = f2b(hB);
        }
    }
}

template<int P4>
__global__ __launch_bounds__(256) void agg1_kernel(
    const int* __restrict__ flags,
    const int* __restrict__ rowptr, const void* __restrict__ csr,
    const void* __restrict__ x,
    const void* W1l, const void* b1l, const void* W1r, const void* b1r,
    const void* We1, const void* att1, const void* bias1, const void* g1v, const void* beta1,
    bf16* __restrict__ hout, int N) {
    if (flags[1]) agg1_body<1, P4>(rowptr, csr, x, W1l, b1l, W1r, b1r,
                                   We1, att1, bias1, g1v, beta1, hout, N);
    else          agg1_body<0, P4>(rowptr, csr, x, W1l, b1l, W1r, b1r,
                                   We1, att1, bias1, g1v, beta1, hout, N);
}

// ---------------- Layer-2 node transform, in-place over hbuf ----------------

template<int F32>
__device__ void node2_body(bf16* __restrict__ hbuf, float* wl, float* wr,
                           const void* W2l, const void* b2l, const void* W2r, const void* b2r,
                           int N) {
    __shared__ float bl[16], br[16];
    int tid = threadIdx.x;
    for (int i = tid; i < 512; i += 256) { wl[i] = ldf<F32>(W2l, i); wr[i] = ldf<F32>(W2r, i); }
    if (tid < 16) { bl[tid] = ldf<F32>(b2l, tid); br[tid] = ldf<F32>(b2r, tid); }
    __syncthreads();
    int n = blockIdx.x * blockDim.x + tid;
    if (n >= N) return;
    float hv[32];
    #pragma unroll
    for (int c = 0; c < 32; ++c) hv[c] = b2f(hbuf[n * 32 + c]);
    float accl[16], accr[16];
    #pragma unroll
    for (int o = 0; o < 16; ++o) { accl[o] = bl[o]; accr[o] = br[o]; }
    #pragma unroll
    for (int c = 0; c < 32; ++c) {
        #pragma unroll
        for (int o = 0; o < 16; ++o) {
            accl[o] = fmaf(hv[c], wl[c * 16 + o], accl[o]);
            accr[o] = fmaf(hv[c], wr[c * 16 + o], accr[o]);
        }
    }
    #pragma unroll
    for (int o = 0; o < 16; ++o) {
        hbuf[n * 32 + o]      = f2b(accl[o]);   // h2l
        hbuf[n * 32 + 16 + o] = f2b(accr[o]);   // h2r
    }
}

__global__ __launch_bounds__(256) void node2_kernel(
    const int* __restrict__ flags, bf16* __restrict__ hbuf,
    const void* W2l, const void* b2l, const void* W2r, const void* b2r, int N) {
    __shared__ float wl[512], wr[512];
    if (flags[1]) node2_body<1>(hbuf, wl, wr, W2l, b2l, W2r, b2r, N);
    else          node2_body<0>(hbuf, wl, wr, W2l, b2l, W2r, b2r, N);
}

// ---------------- Layer-2 aggregation: 4 sub-groups of 16 lanes ----------------

template<int F32, int P4>
__device__ void agg2_body(
    const int* __restrict__ rowptr, const void* __restrict__ csr,
    const bf16* __restrict__ h2,
    const void* We2, const void* att2, const void* bias2, const void* g2v, const void* beta2,
    void* __restrict__ out, int N) {
    int w0 = __builtin_amdgcn_readfirstlane((blockIdx.x * blockDim.x + threadIdx.x) >> 6);
    int NW = (gridDim.x * blockDim.x) >> 6;
    int lane = threadIdx.x & 63;
    int g = lane >> 4, t = lane & 15;

    float we = ldf<F32>(We2, t), at = ldf<F32>(att2, t);
    float bia = ldf<F32>(bias2, t), gg = ldf<F32>(g2v, t), bb = ldf<F32>(beta2, t);

    for (int n = w0; n < N; n += NW) {
        int beg = rowptr[n], end = rowptr[n + 1];
        float xr = b2f(h2[n * 32 + 16 + t]);   // h2r

        float S = 0.f, A = 0.f;
        auto edge = [&](float v, float a) {
            float m = fmaf(a, we, v + xr);
            m = fmaxf(m, NEG_SLOPE * m);       // LeakyReLU
            float p = sclamp(red16(m * at), 60.f);
            float e = __expf(p);
            S += e;
            A = fmaf(e, v, A);
        };
        int k = beg + g;
        for (; k + 4 < end; k += 8) {          // 2x batch per sub-group
            int s0, s1; float a0, a1;
            ldrec<P4>(csr, k, s0, a0);
            ldrec<P4>(csr, k + 4, s1, a1);
            float v0 = b2f(h2[s0 * 32 + t]);
            float v1 = b2f(h2[s1 * 32 + t]);
            edge(v0, a0);
            edge(v1, a1);
        }
        if (k < end) {
            int s0; float a0;
            ldrec<P4>(csr, k, s0, a0);
            edge(b2f(h2[s0 * 32 + t]), a0);
        }
        S += __shfl_xor(S, 16); S += __shfl_xor(S, 32);
        A += __shfl_xor(A, 16); A += __shfl_xor(A, 32);
        float val = A / (S + 1e-16f) + bia;    // empty node -> 0 + bias

        float mu = red16(val) * (1.f / 16.f);
        float d = val - mu;
        float var = red16(d * d) * (1.f / 16.f);
        float y = fmaf(d * rsqrtf(var + LN_EPS), gg, bb);
        if (lane < 16) {
            if (F32) ((float*)out)[n * 16 + t] = y;
            else     ((bf16*)out)[n * 16 + t] = f2b(y);
        }
    }
}

template<int P4>
__global__ __launch_bounds__(256) void agg2_kernel(
    const int* __restrict__ flags,
    const int* __restrict__ rowptr, const void* __restrict__ csr,
    const bf16* __restrict__ h2,
    const void* We2, const void* att2, const void* bias2, const void* g2v, const void* beta2,
    void* __restrict__ out, int N) {
    if (flags[1]) agg2_body<1, P4>(rowptr, csr, h2, We2, att2, bias2, g2v, beta2, out, N);
    else          agg2_body<0, P4>(rowptr, csr, h2, We2, att2, bias2, g2v, beta2, out, N);
}

// ---------------- host ----------------

static inline size_t align256(size_t x) { return (x + 255) & ~size_t(255); }

extern "C" void kernel_launch(void* const* d_in, const int* in_sizes, int n_in,
                              void* d_out, int out_size, void* d_ws, size_t ws_size,
                              hipStream_t stream) {
    const void* x     = d_in[0];
    const int*  ei    = (const int*)d_in[1];
    const void* eattr = d_in[2];
    const void* W1l   = d_in[3];
    const void* b1l   = d_in[4];
    const void* W1r   = d_in[5];
    const void* b1r   = d_in[6];
    const void* We1   = d_in[7];
    const void* att1  = d_in[8];
    const void* bias1 = d_in[9];
    const void* g1    = d_in[10];
    const void* beta1 = d_in[11];
    const void* W2l   = d_in[12];
    const void* b2l   = d_in[13];
    const void* W2r   = d_in[14];
    const void* b2r   = d_in[15];
    const void* We2   = d_in[16];
    const void* att2  = d_in[17];
    const void* bias2 = d_in[18];
    const void* g2    = d_in[19];
    const void* beta2 = d_in[20];

    const int N = in_sizes[0] / 2;   // x is (N,2)
    const int E = in_sizes[2];       // edge_attr is (E,1)
    const int B = (N + SCAN_TILE - 1) / SCAN_TILE;   // 49 @ N=50000 (<=256 supported)
    const bool p4 = (N <= 65536);    // 16-bit src + bf16 attr in one dword

    // workspace (~8.8 MB at N=50000, E=1e6 with 4B records)
    char* ws = (char*)d_ws;
    size_t off = 0;
    int* flags  = (int*)(ws + off); off += align256(sizeof(int) * 2);
    int* bsum   = (int*)(ws + off); off += align256(sizeof(int) * 1024);
    int* cnt    = (int*)(ws + off); off += align256(sizeof(int) * (size_t)N);      // doubles as cursor
    int* rowptr = (int*)(ws + off); off += align256(sizeof(int) * (size_t)(N + 1));
    void* csr   = (void*)(ws + off); off += align256((p4 ? 4u : 8u) * (size_t)E);
    bf16* hbuf  = (bf16*)(ws + off); off += align256(sizeof(bf16) * (size_t)N * 32);

    hipMemsetAsync(cnt, 0, sizeof(int) * (size_t)N, stream);

    int eb = (E + 255) / 256;
    hist_kernel<<<eb, 256, 0, stream>>>(ei, (const unsigned short*)x, E, N, flags, cnt);

    scan_partial<<<B, 256, 0, stream>>>(cnt, bsum, N);
    scan_final<<<B, 256, 0, stream>>>(cnt, rowptr, bsum, N, B);

    if (p4) scatter_kernel<1><<<eb, 256, 0, stream>>>(ei, eattr, E, N, flags, cnt, csr);
    else    scatter_kernel<0><<<eb, 256, 0, stream>>>(ei, eattr, E, N, flags, cnt, csr);

    if (p4) agg1_kernel<1><<<2048, 256, 0, stream>>>(flags, rowptr, csr, x,
                                                     W1l, b1l, W1r, b1r, We1, att1,
                                                     bias1, g1, beta1, hbuf, N);
    else    agg1_kernel<0><<<2048, 256, 0, stream>>>(flags, rowptr, csr, x,
                                                     W1l, b1l, W1r, b1r, We1, att1,
                                                     bias1, g1, beta1, hbuf, N);

    node2_kernel<<<(N + 255) / 256, 256, 0, stream>>>(flags, hbuf, W2l, b2l, W2r, b2r, N);

    if (p4) agg2_kernel<1><<<2048, 256, 0, stream>>>(flags, rowptr, csr, hbuf,
                                                     We2, att2, bias2, g2, beta2, d_out, N);
    else    agg2_kernel<0><<<2048, 256, 0, stream>>>(flags, rowptr, csr, hbuf,
                                                     We2, att2, bias2, g2, beta2, d_out, N);
}

// Round 9
// 225.026 us; speedup vs baseline: 2.3662x; 1.3111x over previous
//
#include <hip/hip_runtime.h>
#include <hip/hip_bf16.h>
#include <math.h>

typedef __hip_bfloat16 bf16;

__device__ __forceinline__ float b2f(bf16 v) { return __bfloat162float(v); }
__device__ __forceinline__ bf16  f2b(float v) { return __float2bfloat16(v); }

template<int F32>
__device__ __forceinline__ float ldf(const void* p, int i) {
    return F32 ? ((const float*)p)[i] : b2f(((const bf16*)p)[i]);
}
// load x[2s], x[2s+1] as one dword (bf16) or dwordx2 (f32)
template<int F32>
__device__ __forceinline__ void ldx(const void* x, int s, float& x0, float& x1) {
    if (F32) { float2 v = ((const float2*)x)[s]; x0 = v.x; x1 = v.y; }
    else {
        unsigned u = ((const unsigned*)x)[s];
        x0 = __uint_as_float((u & 0xFFFFu) << 16);
        x1 = __uint_as_float(u & 0xFFFF0000u);
    }
}
// f32 -> bf16 bits (RNE), returned in HIGH 16 bits
__device__ __forceinline__ unsigned f2b_hi(float f) {
    unsigned u = __float_as_uint(f);
    u += 0x7FFFu + ((u >> 16) & 1u);
    return u & 0xFFFF0000u;
}
// CSR record: P4 -> 4B (attr_hi16 | src16, needs N<=65536); else 8B (src, attr_f32bits)
template<int P4>
__device__ __forceinline__ void ldrec(const void* csr, int k, int& s, float& a) {
    if (P4) {
        unsigned u = ((const unsigned*)csr)[k];
        s = (int)(u & 0xFFFFu);
        a = __uint_as_float(u & 0xFFFF0000u);
    } else {
        uint2 r = ((const uint2*)csr)[k];
        s = (int)r.x;
        a = __uint_as_float(r.y);
    }
}
__device__ __forceinline__ float sclamp(float v, float lim) {
    return fminf(fmaxf(v, -lim), lim);
}
// VALU-only sum over each 16-lane row
template<int CTRL>
__device__ __forceinline__ float dpp_add(float v) {
    int t = __builtin_amdgcn_update_dpp(0, __float_as_int(v), CTRL, 0xF, 0xF, true);
    return v + __int_as_float(t);
}
__device__ __forceinline__ float red16(float v) {
    v = dpp_add<0xB1>(v);    // quad_perm [1,0,3,2]
    v = dpp_add<0x4E>(v);    // quad_perm [2,3,0,1]
    v = dpp_add<0x124>(v);   // row_ror:4
    v = dpp_add<0x128>(v);   // row_ror:8
    return v;
}

#define NEG_SLOPE 0.2f
#define LN_EPS 1e-5f
#define SCAN_TILE 1024
#define ACHUNK 4096     // edges per bucket-bin block

__device__ __forceinline__ int ld_idx(const int* ei, long long pos, int is64, int N) {
    int v = is64 ? ei[2 * pos] : ei[pos];
    return min(max(v, 0), N - 1);
}
__device__ __forceinline__ int calc_is64(const int* ei) {
    int hi = 0, nz = 0;
    #pragma unroll
    for (int i = 0; i < 8; ++i) { hi |= ei[2 * i + 1]; nz |= ei[2 * i]; }
    return (hi == 0 && nz != 0) ? 1 : 0;
}

// ================= bucketed CSR build (N <= 65536): all scatter in LDS =================
// bucket = dst >> 8 (256 nodes/bucket, <=256 buckets)

__global__ __launch_bounds__(256) void histb_kernel(const int* __restrict__ ei,
                                                    const unsigned short* __restrict__ xu,
                                                    int E, int N, int* __restrict__ flags,
                                                    int* __restrict__ bcnt) {
    __shared__ int c[256];
    int tid = threadIdx.x;
    c[tid] = 0;
    int is64 = calc_is64(ei);
    if (blockIdx.x == 0 && tid == 0) {
        flags[0] = is64;
        int pl = 0;
        for (int i = 0; i < 32; ++i) {
            unsigned ex = (xu[2 * i] >> 7) & 0xFF;
            if (ex >= 100 && ex <= 140) pl++;
        }
        flags[1] = (pl >= 24) ? 0 : 1;   // 1 = float tensors are fp32
    }
    __syncthreads();
    int i0 = blockIdx.x * ACHUNK;
    int iend = min(i0 + ACHUNK, E);
    for (int i = i0 + tid; i < iend; i += 256)
        atomicAdd(&c[ld_idx(ei, (long long)E + i, is64, N) >> 8], 1);
    __syncthreads();
    if (c[tid]) atomicAdd(&bcnt[tid], c[tid]);
}

__global__ void scanb_kernel(const int* __restrict__ bcnt, int* __restrict__ bbase,
                             int* __restrict__ bcursor, int* __restrict__ rowptr,
                             int N, int E) {
    __shared__ int s[256];
    int tid = threadIdx.x;
    int v = bcnt[tid];
    s[tid] = v;
    __syncthreads();
    for (int off = 1; off < 256; off <<= 1) {
        int u = (tid >= off) ? s[tid - off] : 0;
        __syncthreads();
        s[tid] += u;
        __syncthreads();
    }
    int excl = s[tid] - v;
    bbase[tid] = excl;
    bcursor[tid] = excl;
    if (tid == 255) { bbase[256] = s[255]; rowptr[N] = E; }
}

// bin 4096 edges via LDS into per-bucket runs; one global atomic + dense run-write per bucket
template<int F32>
__device__ void bina_body(const int* __restrict__ ei, const void* __restrict__ attr,
                          int E, int N, int is64, int* __restrict__ bcursor,
                          uint2* __restrict__ binned) {
    __shared__ int cnt[256], incl[256], cur[256];
    __shared__ uint2 stage[ACHUNK];   // 32 KB
    int tid = threadIdx.x;
    cnt[tid] = 0;
    __syncthreads();
    int i0 = blockIdx.x * ACHUNK;
    int iend = min(i0 + ACHUNK, E);
    for (int i = i0 + tid; i < iend; i += 256)
        atomicAdd(&cnt[ld_idx(ei, (long long)E + i, is64, N) >> 8], 1);
    __syncthreads();
    incl[tid] = cnt[tid];
    __syncthreads();
    for (int off = 1; off < 256; off <<= 1) {
        int u = (tid >= off) ? incl[tid - off] : 0;
        __syncthreads();
        incl[tid] += u;
        __syncthreads();
    }
    cur[tid] = incl[tid] - cnt[tid];
    __syncthreads();
    for (int i = i0 + tid; i < iend; i += 256) {
        int d = ld_idx(ei, (long long)E + i, is64, N);
        int s = ld_idx(ei, (long long)i, is64, N);
        float a = ldf<F32>(attr, i);
        int p = atomicAdd(&cur[d >> 8], 1);
        stage[p] = make_uint2((unsigned)s | ((unsigned)(d & 255) << 16), f2b_hi(a));
    }
    __syncthreads();
    int c = cnt[tid];
    if (c > 0) {
        int start = incl[tid] - c;
        int g = atomicAdd(&bcursor[tid], c);
        for (int j = 0; j < c; ++j) binned[g + j] = stage[start + j];
    }
}

__global__ __launch_bounds__(256) void bina_kernel(const int* __restrict__ ei,
                                                   const void* __restrict__ attr,
                                                   int E, int N, const int* __restrict__ flags,
                                                   int* __restrict__ bcursor,
                                                   uint2* __restrict__ binned) {
    if (flags[1]) bina_body<1>(ei, attr, E, N, flags[0], bcursor, binned);
    else          bina_body<0>(ei, attr, E, N, flags[0], bcursor, binned);
}

// per-bucket: LDS node counters -> rowptr + dense final 4B records
__global__ __launch_bounds__(256) void passb_kernel(const uint2* __restrict__ binned,
                                                    const int* __restrict__ bbase,
                                                    int* __restrict__ rowptr,
                                                    unsigned* __restrict__ csr, int N) {
    __shared__ int nc[256], incl[256], cur[256];
    int b = blockIdx.x, tid = threadIdx.x;
    int base = bbase[b], cntb = bbase[b + 1] - base;
    nc[tid] = 0;
    __syncthreads();
    for (int i = tid; i < cntb; i += 256)
        atomicAdd(&nc[(binned[base + i].x >> 16) & 255], 1);
    __syncthreads();
    incl[tid] = nc[tid];
    __syncthreads();
    for (int off = 1; off < 256; off <<= 1) {
        int u = (tid >= off) ? incl[tid - off] : 0;
        __syncthreads();
        incl[tid] += u;
        __syncthreads();
    }
    int excl = incl[tid] - nc[tid];
    int node = (b << 8) + tid;
    if (node < N) rowptr[node] = base + excl;
    cur[tid] = excl;
    __syncthreads();
    for (int i = tid; i < cntb; i += 256) {
        uint2 r = binned[base + i];
        int p = atomicAdd(&cur[(r.x >> 16) & 255], 1);
        csr[base + p] = r.y | (r.x & 0xFFFFu);
    }
}

// ================= fallback CSR build (N > 65536): r8 path =================

__global__ void hist_kernel(const int* __restrict__ ei, const unsigned short* __restrict__ xu,
                            int E, int N, int* __restrict__ flags, int* __restrict__ cnt) {
    int is64 = calc_is64(ei);
    if (blockIdx.x == 0 && threadIdx.x == 0) {
        flags[0] = is64;
        int pl = 0;
        for (int i = 0; i < 32; ++i) {
            unsigned ex = (xu[2 * i] >> 7) & 0xFF;
            if (ex >= 100 && ex <= 140) pl++;
        }
        flags[1] = (pl >= 24) ? 0 : 1;
    }
    int e = blockIdx.x * blockDim.x + threadIdx.x;
    if (e >= E) return;
    atomicAdd(&cnt[ld_idx(ei, (long long)E + e, is64, N)], 1);
}

__global__ __launch_bounds__(256) void scan_partial(const int* __restrict__ cnt,
                                                    int* __restrict__ bsum, int N) {
    __shared__ int wsum[4];
    int b = blockIdx.x, tid = threadIdx.x;
    int base = b * SCAN_TILE + tid * 4;
    int4 v = make_int4(0, 0, 0, 0);
    if (base + 3 < N) v = *(const int4*)(cnt + base);
    else {
        if (base + 0 < N) v.x = cnt[base + 0];
        if (base + 1 < N) v.y = cnt[base + 1];
        if (base + 2 < N) v.z = cnt[base + 2];
    }
    int s = v.x + v.y + v.z + v.w;
    #pragma unroll
    for (int off = 1; off < 64; off <<= 1) s += __shfl_xor(s, off);
    if ((tid & 63) == 0) wsum[tid >> 6] = s;
    __syncthreads();
    if (tid == 0) bsum[b] = wsum[0] + wsum[1] + wsum[2] + wsum[3];
}

__global__ __launch_bounds__(256) void scan_final(int* __restrict__ cnt, int* __restrict__ rowptr,
                                                  const int* __restrict__ bsum, int N, int B) {
    __shared__ int tsum[256];
    __shared__ int bpre[256];
    int b = blockIdx.x, tid = threadIdx.x;
    bpre[tid] = (tid < B) ? bsum[tid] : 0;
    int base = b * SCAN_TILE + tid * 4;
    int4 v = make_int4(0, 0, 0, 0);
    if (base + 3 < N) v = *(const int4*)(cnt + base);
    else {
        if (base + 0 < N) v.x = cnt[base + 0];
        if (base + 1 < N) v.y = cnt[base + 1];
        if (base + 2 < N) v.z = cnt[base + 2];
    }
    tsum[tid] = v.x + v.y + v.z + v.w;
    __syncthreads();
    for (int off = 1; off < 256; off <<= 1) {
        int t = (tid >= off) ? tsum[tid - off] : 0;
        int u = (tid >= off) ? bpre[tid - off] : 0;
        __syncthreads();
        tsum[tid] += t;
        bpre[tid] += u;
        __syncthreads();
    }
    int blockpre = (b == 0) ? 0 : bpre[b - 1];
    int o0 = blockpre + ((tid == 0) ? 0 : tsum[tid - 1]);
    int o1 = o0 + v.x, o2 = o1 + v.y, o3 = o2 + v.z;
    if (base + 3 < N) {
        int4 o = make_int4(o0, o1, o2, o3);
        *(int4*)(rowptr + base) = o;
        *(int4*)(cnt + base) = o;
    } else {
        if (base + 0 < N) { rowptr[base + 0] = o0; cnt[base + 0] = o0; }
        if (base + 1 < N) { rowptr[base + 1] = o1; cnt[base + 1] = o1; }
        if (base + 2 < N) { rowptr[base + 2] = o2; cnt[base + 2] = o2; }
    }
    if (b == 0 && tid == 255) rowptr[N] = bpre[255];
}

template<int F32>
__device__ void scatter_body(const int* __restrict__ ei, const void* __restrict__ attr,
                             int E, int N, int is64, int* __restrict__ cursor,
                             uint2* __restrict__ csr) {
    int e = blockIdx.x * blockDim.x + threadIdx.x;
    if (e >= E) return;
    int d = ld_idx(ei, (long long)E + e, is64, N);
    int s = ld_idx(ei, (long long)e, is64, N);
    float av = ldf<F32>(attr, e);
    int pos = atomicAdd(&cursor[d], 1);
    csr[pos] = make_uint2((unsigned)s, __float_as_uint(av));
}

__global__ void scatter_kernel(const int* __restrict__ ei, const void* __restrict__ attr,
                               int E, int N, const int* __restrict__ flags,
                               int* __restrict__ cursor, uint2* __restrict__ csr) {
    if (flags[1]) scatter_body<1>(ei, attr, E, N, flags[0], cursor, csr);
    else          scatter_body<0>(ei, attr, E, N, flags[0], cursor, csr);
}

// ================= Layer-1 aggregation =================

template<int F32, int P4>
__device__ void agg1_body(
    const int* __restrict__ rowptr, const void* __restrict__ csr,
    const void* __restrict__ x,
    const void* W1l, const void* b1l, const void* W1r, const void* b1r,
    const void* We1, const void* att1, const void* bias1, const void* g1v, const void* beta1,
    bf16* __restrict__ hout, int N) {
    int w0 = __builtin_amdgcn_readfirstlane((blockIdx.x * blockDim.x + threadIdx.x) >> 6);
    int NW = (gridDim.x * blockDim.x) >> 6;
    int lane = threadIdx.x & 63;
    int h = lane >> 4, q = lane & 15;
    int ja = h * 32 + q, jb = ja + 16;

    float wlaA = ldf<F32>(W1l, ja),      wlaB = ldf<F32>(W1l, jb);
    float wlbA = ldf<F32>(W1l, 128 + ja), wlbB = ldf<F32>(W1l, 128 + jb);
    float wraA = ldf<F32>(W1r, ja),      wraB = ldf<F32>(W1r, jb);
    float wrbA = ldf<F32>(W1r, 128 + ja), wrbB = ldf<F32>(W1r, 128 + jb);
    float blA = ldf<F32>(b1l, ja), blB = ldf<F32>(b1l, jb);
    float brA = ldf<F32>(b1r, ja), brB = ldf<F32>(b1r, jb);
    float weA = ldf<F32>(We1, ja), weB = ldf<F32>(We1, jb);
    float atA = ldf<F32>(att1, ja), atB = ldf<F32>(att1, jb);
    float aa4A = 0.4f * atA, aa4B = 0.4f * atB;
    float blbrA = blA + brA, blbrB = blB + brB;
    float P0 = 0.6f * red16(atA * wlaA + atB * wlaB);
    float P1 = 0.6f * red16(atA * wlbA + atB * wlbB);
    float Pw = 0.6f * red16(atA * weA + atB * weB);
    float Q0 = 0.6f * red16(atA * wraA + atB * wraB);
    float Q1 = 0.6f * red16(atA * wrbA + atB * wrbB);
    float Qc = 0.6f * red16(atA * blbrA + atB * blbrB);
    float biasA = ldf<F32>(bias1, q), biasB = ldf<F32>(bias1, q + 16);
    float gA = ldf<F32>(g1v, q), gB = ldf<F32>(g1v, q + 16);
    float beA = ldf<F32>(beta1, q), beB = ldf<F32>(beta1, q + 16);

    for (int n = w0; n < N; n += NW) {
        int beg = rowptr[n], end = rowptr[n + 1];
        float xd0, xd1;
        ldx<F32>(x, n, xd0, xd1);
        float cA = fmaf(xd0, wraA, fmaf(xd1, wrbA, blbrA));
        float cB = fmaf(xd0, wraB, fmaf(xd1, wrbB, blbrB));
        float Kn = fmaf(xd0, Q0, fmaf(xd1, Q1, Qc));
        float S = 0.f, Sx0 = 0.f, Sx1 = 0.f;

        auto edge = [&](float xs0, float xs1, float a) {
            float zA = fmaf(xs0, wlaA, fmaf(xs1, wlbA, fmaf(a, weA, cA)));
            float zB = fmaf(xs0, wlaB, fmaf(xs1, wlbB, fmaf(a, weB, cB)));
            float pabs = red16(fmaf(fabsf(zA), aa4A, fabsf(zB) * aa4B));
            float p = sclamp(fmaf(xs0, P0, fmaf(xs1, P1, fmaf(a, Pw, Kn))) + pabs, 60.f);
            float e = __expf(p);
            S += e;
            Sx0 = fmaf(e, xs0, Sx0);
            Sx1 = fmaf(e, xs1, Sx1);
        };

        int k = beg;
        for (; k + 4 <= end; k += 4) {
            int s0, s1, s2, s3;
            float a0, a1, a2, a3;
            ldrec<P4>(csr, k, s0, a0);
            ldrec<P4>(csr, k + 1, s1, a1);
            ldrec<P4>(csr, k + 2, s2, a2);
            ldrec<P4>(csr, k + 3, s3, a3);
            float p0, p1, q0, q1, r0, r1, t0, t1;
            ldx<F32>(x, s0, p0, p1);
            ldx<F32>(x, s1, q0, q1);
            ldx<F32>(x, s2, r0, r1);
            ldx<F32>(x, s3, t0, t1);
            edge(p0, p1, a0);
            edge(q0, q1, a1);
            edge(r0, r1, a2);
            edge(t0, t1, a3);
        }
        for (; k < end; ++k) {
            int s0; float a0;
            ldrec<P4>(csr, k, s0, a0);
            float p0, p1;
            ldx<F32>(x, s0, p0, p1);
            edge(p0, p1, a0);
        }

        float inv = 1.0f / (S + 1e-16f);
        float R = S * inv, U0 = Sx0 * inv, U1 = Sx1 * inv;
        float outA = fmaf(U0, wlaA, fmaf(U1, wlbA, R * blA));
        float outB = fmaf(U0, wlaB, fmaf(U1, wlbB, R * blB));
        outA += __shfl_xor(outA, 16); outA += __shfl_xor(outA, 32);
        outB += __shfl_xor(outB, 16); outB += __shfl_xor(outB, 32);
        float valA = fmaf(0.25f, outA, biasA);
        float valB = fmaf(0.25f, outB, biasB);
        float mu = red16(valA + valB) * (1.f / 32.f);
        float dA = valA - mu, dB = valB - mu;
        float var = red16(dA * dA + dB * dB) * (1.f / 32.f);
        float rs = rsqrtf(var + LN_EPS);
        float yA = fmaf(dA * rs, gA, beA);
        float yB = fmaf(dB * rs, gB, beB);
        float hA = yA > 0.f ? yA : expm1f(yA);
        float hB = yB > 0.f ? yB : expm1f(yB);
        if (lane < 16) {
            hout[n * 32 + q]      = f2b(hA);
            hout[n * 32 + 16 + q] = f2b(hB);
        }
    }
}

template<int P4>
__global__ __launch_bounds__(256) void agg1_kernel(
    const int* __restrict__ flags,
    const int* __restrict__ rowptr, const void* __restrict__ csr,
    const void* __restrict__ x,
    const void* W1l, const void* b1l, const void* W1r, const void* b1r,
    const void* We1, const void* att1, const void* bias1, const void* g1v, const void* beta1,
    bf16* __restrict__ hout, int N) {
    if (flags[1]) agg1_body<1, P4>(rowptr, csr, x, W1l, b1l, W1r, b1r,
                                   We1, att1, bias1, g1v, beta1, hout, N);
    else          agg1_body<0, P4>(rowptr, csr, x, W1l, b1l, W1r, b1r,
                                   We1, att1, bias1, g1v, beta1, hout, N);
}

// ================= Layer-2 node transform, in-place over hbuf =================

template<int F32>
__device__ void node2_body(bf16* __restrict__ hbuf, float* wl, float* wr,
                           const void* W2l, const void* b2l, const void* W2r, const void* b2r,
                           int N) {
    __shared__ float bl[16], br[16];
    int tid = threadIdx.x;
    for (int i = tid; i < 512; i += 256) { wl[i] = ldf<F32>(W2l, i); wr[i] = ldf<F32>(W2r, i); }
    if (tid < 16) { bl[tid] = ldf<F32>(b2l, tid); br[tid] = ldf<F32>(b2r, tid); }
    __syncthreads();
    int n = blockIdx.x * blockDim.x + tid;
    if (n >= N) return;
    float hv[32];
    #pragma unroll
    for (int c = 0; c < 32; ++c) hv[c] = b2f(hbuf[n * 32 + c]);
    float accl[16], accr[16];
    #pragma unroll
    for (int o = 0; o < 16; ++o) { accl[o] = bl[o]; accr[o] = br[o]; }
    #pragma unroll
    for (int c = 0; c < 32; ++c) {
        #pragma unroll
        for (int o = 0; o < 16; ++o) {
            accl[o] = fmaf(hv[c], wl[c * 16 + o], accl[o]);
            accr[o] = fmaf(hv[c], wr[c * 16 + o], accr[o]);
        }
    }
    #pragma unroll
    for (int o = 0; o < 16; ++o) {
        hbuf[n * 32 + o]      = f2b(accl[o]);   // h2l
        hbuf[n * 32 + 16 + o] = f2b(accr[o]);   // h2r
    }
}

__global__ __launch_bounds__(256) void node2_kernel(
    const int* __restrict__ flags, bf16* __restrict__ hbuf,
    const void* W2l, const void* b2l, const void* W2r, const void* b2r, int N) {
    __shared__ float wl[512], wr[512];
    if (flags[1]) node2_body<1>(hbuf, wl, wr, W2l, b2l, W2r, b2r, N);
    else          node2_body<0>(hbuf, wl, wr, W2l, b2l, W2r, b2r, N);
}

// ================= Layer-2 aggregation =================

template<int F32, int P4>
__device__ void agg2_body(
    const int* __restrict__ rowptr, const void* __restrict__ csr,
    const bf16* __restrict__ h2,
    const void* We2, const void* att2, const void* bias2, const void* g2v, const void* beta2,
    void* __restrict__ out, int N) {
    int w0 = __builtin_amdgcn_readfirstlane((blockIdx.x * blockDim.x + threadIdx.x) >> 6);
    int NW = (gridDim.x * blockDim.x) >> 6;
    int lane = threadIdx.x & 63;
    int g = lane >> 4, t = lane & 15;

    float we = ldf<F32>(We2, t), at = ldf<F32>(att2, t);
    float bia = ldf<F32>(bias2, t), gg = ldf<F32>(g2v, t), bb = ldf<F32>(beta2, t);

    for (int n = w0; n < N; n += NW) {
        int beg = rowptr[n], end = rowptr[n + 1];
        float xr = b2f(h2[n * 32 + 16 + t]);   // h2r

        float S = 0.f, A = 0.f;
        auto edge = [&](float v, float a) {
            float m = fmaf(a, we, v + xr);
            m = fmaxf(m, NEG_SLOPE * m);
            float p = sclamp(red16(m * at), 60.f);
            float e = __expf(p);
            S += e;
            A = fmaf(e, v, A);
        };
        int k = beg + g;
        for (; k + 4 < end; k += 8) {
            int s0, s1; float a0, a1;
            ldrec<P4>(csr, k, s0, a0);
            ldrec<P4>(csr, k + 4, s1, a1);
            float v0 = b2f(h2[s0 * 32 + t]);
            float v1 = b2f(h2[s1 * 32 + t]);
            edge(v0, a0);
            edge(v1, a1);
        }
        if (k < end) {
            int s0; float a0;
            ldrec<P4>(csr, k, s0, a0);
            edge(b2f(h2[s0 * 32 + t]), a0);
        }
        S += __shfl_xor(S, 16); S += __shfl_xor(S, 32);
        A += __shfl_xor(A, 16); A += __shfl_xor(A, 32);
        float val = A / (S + 1e-16f) + bia;

        float mu = red16(val) * (1.f / 16.f);
        float d = val - mu;
        float var = red16(d * d) * (1.f / 16.f);
        float y = fmaf(d * rsqrtf(var + LN_EPS), gg, bb);
        if (lane < 16) {
            if (F32) ((float*)out)[n * 16 + t] = y;
            else     ((bf16*)out)[n * 16 + t] = f2b(y);
        }
    }
}

template<int P4>
__global__ __launch_bounds__(256) void agg2_kernel(
    const int* __restrict__ flags,
    const int* __restrict__ rowptr, const void* __restrict__ csr,
    const bf16* __restrict__ h2,
    const void* We2, const void* att2, const void* bias2, const void* g2v, const void* beta2,
    void* __restrict__ out, int N) {
    if (flags[1]) agg2_body<1, P4>(rowptr, csr, h2, We2, att2, bias2, g2v, beta2, out, N);
    else          agg2_body<0, P4>(rowptr, csr, h2, We2, att2, bias2, g2v, beta2, out, N);
}

// ================= host =================

static inline size_t align256(size_t x) { return (x + 255) & ~size_t(255); }

extern "C" void kernel_launch(void* const* d_in, const int* in_sizes, int n_in,
                              void* d_out, int out_size, void* d_ws, size_t ws_size,
                              hipStream_t stream) {
    const void* x     = d_in[0];
    const int*  ei    = (const int*)d_in[1];
    const void* eattr = d_in[2];
    const void* W1l   = d_in[3];
    const void* b1l   = d_in[4];
    const void* W1r   = d_in[5];
    const void* b1r   = d_in[6];
    const void* We1   = d_in[7];
    const void* att1  = d_in[8];
    const void* bias1 = d_in[9];
    const void* g1    = d_in[10];
    const void* beta1 = d_in[11];
    const void* W2l   = d_in[12];
    const void* b2l   = d_in[13];
    const void* W2r   = d_in[14];
    const void* b2r   = d_in[15];
    const void* We2   = d_in[16];
    const void* att2  = d_in[17];
    const void* bias2 = d_in[18];
    const void* g2    = d_in[19];
    const void* beta2 = d_in[20];

    const int N = in_sizes[0] / 2;   // x is (N,2)
    const int E = in_sizes[2];       // edge_attr is (E,1)
    const bool p4 = (N <= 65536);
    const int EB = (E + ACHUNK - 1) / ACHUNK;   // bucket-bin blocks

    char* ws = (char*)d_ws;
    size_t off = 0;
    int* flags   = (int*)(ws + off); off += align256(sizeof(int) * 2);
    int* bcnt    = (int*)(ws + off); off += align256(sizeof(int) * 1024);  // bucket cnts / bsum
    int* bbase   = (int*)(ws + off); off += align256(sizeof(int) * 257);
    int* bcursor = (int*)(ws + off); off += align256(sizeof(int) * 256);
    int* rowptr  = (int*)(ws + off); off += align256(sizeof(int) * (size_t)(N + 1));
    void* csr    = (void*)(ws + off); off += align256((p4 ? 4u : 8u) * (size_t)E);
    char* big    = (ws + off);   // shared region: binned (p4) / cnt (fallback) / hbuf
    uint2* binned = (uint2*)big;                       // 8E bytes, dead after passb
    int*   cnt    = (int*)big;                         // fallback cursor array (N ints)
    bf16*  hbuf   = (bf16*)big;                        // N*32 bf16, written after binned dies

    if (p4) {
        hipMemsetAsync(bcnt, 0, sizeof(int) * 256, stream);
        histb_kernel<<<EB, 256, 0, stream>>>(ei, (const unsigned short*)x, E, N, flags, bcnt);
        scanb_kernel<<<1, 256, 0, stream>>>(bcnt, bbase, bcursor, rowptr, N, E);
        bina_kernel<<<EB, 256, 0, stream>>>(ei, eattr, E, N, flags, bcursor, binned);
        passb_kernel<<<(N + 255) >> 8, 256, 0, stream>>>(binned, bbase, rowptr, (unsigned*)csr, N);
    } else {
        // fallback: hbuf must not alias cnt — place hbuf after cnt in the big region
        cnt = (int*)big;
        hbuf = (bf16*)(big + align256(sizeof(int) * (size_t)N));
        const int B = (N + SCAN_TILE - 1) / SCAN_TILE;
        hipMemsetAsync(cnt, 0, sizeof(int) * (size_t)N, stream);
        hist_kernel<<<(E + 255) / 256, 256, 0, stream>>>(ei, (const unsigned short*)x, E, N, flags, cnt);
        scan_partial<<<B, 256, 0, stream>>>(cnt, bcnt, N);
        scan_final<<<B, 256, 0, stream>>>(cnt, rowptr, bcnt, N, B);
        scatter_kernel<<<(E + 255) / 256, 256, 0, stream>>>(ei, eattr, E, N, flags, cnt, (uint2*)csr);
    }

    if (p4) agg1_kernel<1><<<2048, 256, 0, stream>>>(flags, rowptr, csr, x,
                                                     W1l, b1l, W1r, b1r, We1, att1,
                                                     bias1, g1, beta1, hbuf, N);
    else    agg1_kernel<0><<<2048, 256, 0, stream>>>(flags, rowptr, csr, x,
                                                     W1l, b1l, W1r, b1r, We1, att1,
                                                     bias1, g1, beta1, hbuf, N);

    node2_kernel<<<(N + 255) / 256, 256, 0, stream>>>(flags, hbuf, W2l, b2l, W2r, b2r, N);

    if (p4) agg2_kernel<1><<<2048, 256, 0, stream>>>(flags, rowptr, csr, hbuf,
                                                     We2, att2, bias2, g2, beta2, d_out, N);
    else    agg2_kernel<0><<<2048, 256, 0, stream>>>(flags, rowptr, csr, hbuf,
                                                     We2, att2, bias2, g2, beta2, d_out, N);
}